// Round 1
// baseline (1085.877 us; speedup 1.0000x reference)
//
#include <hip/hip_runtime.h>

// Problem shapes (fixed):
// x: [4][256][8][28][28] fp32
// tm: [n*8+t][128][784]      (corr-projected, relu'd input)
// m0: [28][3][784]           (relu(sim))
// m1: [28][64][676]   m2/m3: [28][128][676]   m4: [28][256][676]
// out: [4][256] fp32

#define NORM_INV 0.07978845608028654f   // 1/(sqrt(2*pi)*5)

// ---------------------------------------------------------------------------
// Kernel A: tm[n][t][o][hw] = sum_k corr_w[o][k]*relu(x[n][k][t][hw]) + corr_b[o]
// grid (4 pixel tiles, 4 c-chunks of 32, 32 nt), 256 threads
// ---------------------------------------------------------------------------
__global__ __launch_bounds__(256) void tm_kernel(const float* __restrict__ x,
    const float* __restrict__ cw, const float* __restrict__ cb,
    float* __restrict__ tm) {
  const int tid = threadIdx.x;
  const int p = blockIdx.x * 256 + tid;      // pixel 0..783
  const int c0 = blockIdx.y * 32;            // output-channel chunk
  const int nt = blockIdx.z;                 // n*8+t
  const int n = nt >> 3, t = nt & 7;
  __shared__ float wl[256 * 32];             // [k][cc]
  for (int idx = tid; idx < 256 * 32; idx += 256) {
    const int cc = idx & 31, k = idx >> 5;
    wl[idx] = cw[(c0 + cc) * 256 + k];
  }
  __syncthreads();
  if (p >= 784) return;
  float acc[32];
#pragma unroll
  for (int i = 0; i < 32; ++i) acc[i] = 0.f;
  const float* xp = x + ((size_t)n * 2048 + t) * 784 + p;  // k-stride 6272
#pragma unroll 4
  for (int k = 0; k < 256; ++k) {
    const float xv = fmaxf(xp[(size_t)k * 6272], 0.f);
    const float* w = &wl[k * 32];
#pragma unroll
    for (int c4 = 0; c4 < 32; c4 += 4) {
      const float4 wv = *(const float4*)&w[c4];
      acc[c4 + 0] += wv.x * xv; acc[c4 + 1] += wv.y * xv;
      acc[c4 + 2] += wv.z * xv; acc[c4 + 3] += wv.w * xv;
    }
  }
  float* op = tm + ((size_t)nt * 128 + c0) * 784 + p;
#pragma unroll
  for (int cc = 0; cc < 32; ++cc) op[(size_t)cc * 784] = acc[cc] + cb[c0 + cc];
}

// ---------------------------------------------------------------------------
// Kernel B: fused score GEMM + argmax + double softmax -> relu(sim) = m0
// block = one (n,t) + 8 uv pixels. score tile 8x784 lives in LDS only.
// grid (98, 28), 256 threads
// ---------------------------------------------------------------------------
__global__ __launch_bounds__(256) void score_kernel(const float* __restrict__ tm,
    float* __restrict__ m0) {
  const int tid = threadIdx.x;
  const int nt = blockIdx.y;                 // 0..27
  const int n = nt / 7, t = nt % 7;
  const int uv0 = blockIdx.x * 8;
  const float* Ap = tm + (size_t)(n * 8 + t) * 128 * 784;      // bf (uv side)
  const float* Bp = tm + (size_t)(n * 8 + t + 1) * 128 * 784;  // bh (ab side)
  __shared__ float Al[128 * 8];              // A fragment [c][u]
  __shared__ float sc[8 * 784];              // score tile [u][ab]
  for (int idx = tid; idx < 1024; idx += 256) {
    const int u = idx & 7, c = idx >> 3;
    Al[idx] = Ap[c * 784 + uv0 + u];
  }
  __syncthreads();
  // ---- GEMM: sc[u][ab] = sum_c A[c][uv0+u]*B[c][ab]
  float acc[8][4];
#pragma unroll
  for (int u = 0; u < 8; ++u)
#pragma unroll
    for (int j = 0; j < 4; ++j) acc[u][j] = 0.f;
  const bool v3 = tid < 16;                  // ab=768+tid valid
  for (int c = 0; c < 128; ++c) {
    const float4 a0 = *(const float4*)&Al[c * 8];
    const float4 a1 = *(const float4*)&Al[c * 8 + 4];
    const float av[8] = {a0.x, a0.y, a0.z, a0.w, a1.x, a1.y, a1.z, a1.w};
    const float* bp = &Bp[c * 784 + tid];
    float bcv[4];
    bcv[0] = bp[0]; bcv[1] = bp[256]; bcv[2] = bp[512];
    bcv[3] = v3 ? bp[768] : 0.f;
#pragma unroll
    for (int u = 0; u < 8; ++u)
#pragma unroll
      for (int j = 0; j < 4; ++j) acc[u][j] += av[u] * bcv[j];
  }
#pragma unroll
  for (int u = 0; u < 8; ++u) {
    sc[u * 784 + tid] = acc[u][0];
    sc[u * 784 + tid + 256] = acc[u][1];
    sc[u * 784 + tid + 512] = acc[u][2];
    if (v3) sc[u * 784 + tid + 768] = acc[u][3];
  }
  __syncthreads();
  // ---- per-row (uv) reductions: 32 lanes per row
  const int r = tid >> 5, l = tid & 31;
  const float* row = &sc[r * 784];
  float bv = -1e30f; int bi = 0;             // max + first-index argmax
  for (int a2 = l; a2 < 784; a2 += 32) {
    const float v = row[a2];
    if (v > bv) { bv = v; bi = a2; }
  }
#pragma unroll
  for (int off = 16; off; off >>= 1) {
    const float ov = __shfl_xor(bv, off, 32);
    const int oi = __shfl_xor(bi, off, 32);
    if (ov > bv || (ov == bv && oi < bi)) { bv = ov; bi = oi; }
  }
  const int ast = bi / 28;
  const int bst = bi - ast * 28;
  // pass 2: maxes of g*score for both softmaxes
  float mx = -1e30f, my = -1e30f;
  for (int a2 = l; a2 < 784; a2 += 32) {
    const float v = row[a2];
    const int a = a2 / 28; const int bb = a2 - a * 28;
    const float gx = __expf((float)(a - ast) * 0.04f) * NORM_INV;
    const float gy = __expf((float)(bb - bst) * 0.04f) * NORM_INV;
    mx = fmaxf(mx, gx * v); my = fmaxf(my, gy * v);
  }
#pragma unroll
  for (int off = 16; off; off >>= 1) {
    mx = fmaxf(mx, __shfl_xor(mx, off, 32));
    my = fmaxf(my, __shfl_xor(my, off, 32));
  }
  // pass 3: stabilized softmax sums + index-weighted sums
  float sx = 0.f, sxw = 0.f, sy = 0.f, syw = 0.f;
  for (int a2 = l; a2 < 784; a2 += 32) {
    const float v = row[a2];
    const int a = a2 / 28; const int bb = a2 - a * 28;
    const float gx = __expf((float)(a - ast) * 0.04f) * NORM_INV;
    const float gy = __expf((float)(bb - bst) * 0.04f) * NORM_INV;
    const float ex = __expf((gx * v - mx) * 100.f);
    const float ey = __expf((gy * v - my) * 100.f);
    sx += ex; sxw += (float)a * ex;
    sy += ey; syw += (float)bb * ey;
  }
#pragma unroll
  for (int off = 16; off; off >>= 1) {
    sx += __shfl_xor(sx, off, 32); sxw += __shfl_xor(sxw, off, 32);
    sy += __shfl_xor(sy, off, 32); syw += __shfl_xor(syw, off, 32);
  }
  if (l == 0) {
    const int uv = uv0 + r;
    float* op = m0 + (size_t)nt * 3 * 784 + uv;
    op[0]    = fmaxf(sxw / sx, 0.f);   // relu(d_x)
    op[784]  = fmaxf(syw / sy, 0.f);   // relu(d_y)
    op[1568] = fmaxf(bv, 0.f);         // relu(max_score)
  }
}

// ---------------------------------------------------------------------------
// Direct conv, pad=1. Block = (batch, COT output channels); 256 threads cover
// the 676 output pixels in NPG passes. Per-ci: input channel staged in LDS,
// weights LDS-staged once (register-cached per ci when K==3).
// ---------------------------------------------------------------------------
template<int CIN, int K, int HIN, int COT, bool RELU, bool WREG>
__global__ __launch_bounds__(256) void conv_kernel(const float* __restrict__ in,
    const float* __restrict__ wt, const float* __restrict__ bias,
    float* __restrict__ out, int cout) {
  constexpr int K2 = K * K;
  constexpr int HOUT = HIN + 2 - K + 1;
  constexpr int NPIX = HOUT * HOUT;
  constexpr int NPG = (NPIX + 255) / 256;
  constexpr int WSZ = CIN * K2 * COT;
  const int b = blockIdx.y;
  const int co0 = blockIdx.x * COT;
  const int tid = threadIdx.x;
  extern __shared__ float lds[];
  float* wl = lds;            // [ci][tap][col]
  float* il = lds + WSZ;      // [HIN*HIN]
  // stage weights (coalesced reads, scattered LDS writes - once per block)
  for (int gidx = tid; gidx < WSZ; gidx += 256) {
    const int col = gidx / (CIN * K2);
    const int rest = gidx - col * (CIN * K2);
    wl[rest * COT + col] = wt[(size_t)(co0 + col) * (CIN * K2) + rest];
  }
  float acc[NPG][COT];
#pragma unroll
  for (int pg = 0; pg < NPG; ++pg)
#pragma unroll
    for (int c = 0; c < COT; ++c) acc[pg][c] = 0.f;
  int oy[NPG], ox[NPG];
#pragma unroll
  for (int pg = 0; pg < NPG; ++pg) {
    const int pix = pg * 256 + tid;
    oy[pg] = pix / HOUT; ox[pg] = pix - oy[pg] * HOUT;
  }
  for (int ci = 0; ci < CIN; ++ci) {
    __syncthreads();
    const float* ip = in + ((size_t)b * CIN + ci) * (HIN * HIN);
    for (int idx = tid; idx < HIN * HIN; idx += 256) il[idx] = ip[idx];
    __syncthreads();
    if constexpr (WREG) {
      float wr[K2 * COT];
#pragma unroll
      for (int q = 0; q < K2 * COT / 4; ++q)
        *(float4*)&wr[q * 4] = *(const float4*)&wl[ci * (K2 * COT) + q * 4];
#pragma unroll
      for (int pg = 0; pg < NPG; ++pg) {
        if (pg * 256 + tid >= NPIX) break;
#pragma unroll
        for (int dy = 0; dy < K; ++dy) {
          const int iy = oy[pg] + dy - 1;
          if ((unsigned)iy >= (unsigned)HIN) continue;
#pragma unroll
          for (int dx = 0; dx < K; ++dx) {
            const int ix = ox[pg] + dx - 1;
            if ((unsigned)ix >= (unsigned)HIN) continue;
            const float v = il[iy * HIN + ix];
            const int tap = dy * K + dx;
#pragma unroll
            for (int c = 0; c < COT; ++c) acc[pg][c] += v * wr[tap * COT + c];
          }
        }
      }
    } else {
#pragma unroll
      for (int pg = 0; pg < NPG; ++pg) {
        if (pg * 256 + tid >= NPIX) break;
#pragma unroll
        for (int dy = 0; dy < K; ++dy) {
          const int iy = oy[pg] + dy - 1;
          if ((unsigned)iy >= (unsigned)HIN) continue;
#pragma unroll
          for (int dx = 0; dx < K; ++dx) {
            const int ix = ox[pg] + dx - 1;
            if ((unsigned)ix >= (unsigned)HIN) continue;
            const float v = il[iy * HIN + ix];
            const float* wp = &wl[(ci * K2 + dy * K + dx) * COT];
#pragma unroll
            for (int c4 = 0; c4 < COT; c4 += 4) {
              const float4 w = *(const float4*)&wp[c4];
              acc[pg][c4 + 0] += w.x * v; acc[pg][c4 + 1] += w.y * v;
              acc[pg][c4 + 2] += w.z * v; acc[pg][c4 + 3] += w.w * v;
            }
          }
        }
      }
    }
  }
#pragma unroll
  for (int pg = 0; pg < NPG; ++pg) {
    const int pix = pg * 256 + tid;
    if (pix >= NPIX) break;
#pragma unroll
    for (int c = 0; c < COT; ++c) {
      float v = acc[pg][c] + bias[co0 + c];
      if (RELU) v = fmaxf(v, 0.f);
      out[((size_t)b * cout + co0 + c) * NPIX + pix] = v;
    }
  }
}

// ---------------------------------------------------------------------------
// D1: r[n][c] = relu( mean_thw(x) + mean_t,hw(m4) ); one block per (n,c)
// ---------------------------------------------------------------------------
__global__ __launch_bounds__(256) void final_reduce_kernel(const float* __restrict__ x,
    const float* __restrict__ m4, float* __restrict__ r) {
  const int nc = blockIdx.x;
  const int n = nc >> 8, c = nc & 255;
  const int tid = threadIdx.x;
  const float* xs = x + (size_t)nc * 6272;
  float s = 0.f;
  for (int i = tid; i < 6272; i += 256) s += xs[i];
  float s2 = 0.f;
  for (int t = 0; t < 7; ++t) {
    const float* ms = m4 + ((size_t)(n * 7 + t) * 256 + c) * 676;
    for (int i = tid; i < 676; i += 256) s2 += ms[i];
  }
  float v = s * (1.f / 6272.f) + s2 * (1.f / 4732.f);
#pragma unroll
  for (int off = 32; off; off >>= 1) v += __shfl_down(v, off);
  __shared__ float red[4];
  if ((tid & 63) == 0) red[tid >> 6] = v;
  __syncthreads();
  if (tid == 0) r[nc] = fmaxf(red[0] + red[1] + red[2] + red[3], 0.f);
}

// ---------------------------------------------------------------------------
// D2: z[n][j] = lin_b[j] + sum_c r[n][c]*lin_w[j][c]; one block per n
// ---------------------------------------------------------------------------
__global__ __launch_bounds__(256) void linear_kernel(const float* __restrict__ r,
    const float* __restrict__ lw, const float* __restrict__ lb,
    float* __restrict__ out) {
  const int n = blockIdx.x;
  const int j = threadIdx.x;
  __shared__ float rl[256];
  rl[j] = r[n * 256 + j];
  __syncthreads();
  float acc = lb[j];
  const float* w = lw + (size_t)j * 256;
#pragma unroll 4
  for (int c = 0; c < 256; c += 4) {
    const float4 wv = *(const float4*)&w[c];
    acc += wv.x * rl[c] + wv.y * rl[c + 1] + wv.z * rl[c + 2] + wv.w * rl[c + 3];
  }
  out[n * 256 + j] = acc;
}

extern "C" void kernel_launch(void* const* d_in, const int* in_sizes, int n_in,
                              void* d_out, int out_size, void* d_ws, size_t ws_size,
                              hipStream_t stream) {
  const float* x      = (const float*)d_in[0];
  const float* corr_w = (const float*)d_in[1];
  const float* corr_b = (const float*)d_in[2];
  const float* mw1 = (const float*)d_in[3];
  const float* mb1 = (const float*)d_in[4];
  const float* mw2 = (const float*)d_in[5];
  const float* mb2 = (const float*)d_in[6];
  const float* mw3 = (const float*)d_in[7];
  const float* mb3 = (const float*)d_in[8];
  const float* mw4 = (const float*)d_in[9];
  const float* mb4 = (const float*)d_in[10];
  const float* lin_w = (const float*)d_in[11];
  const float* lin_b = (const float*)d_in[12];
  float* out = (float*)d_out;
  float* ws = (float*)d_ws;
  // aliased workspace (floats). Peak use 9,694,208 floats = 37 MB.
  float* tm = ws;                // [0, 3211264)
  float* m0 = ws + 3211264;      // [3211264, 3277120)
  float* m1 = ws + 3277120;      // [3277120, 4488768)
  float* m2 = ws;                // [0, 2423296)        tm dead
  float* m3 = ws + 2423296;      // [2423296, 4846592)  m0/m1 dead by conv3
  float* m4 = ws + 4846592;      // [4846592, 9693184)
  float* rr = ws + 9693184;      // [9693184, 9694208)

  tm_kernel<<<dim3(4, 4, 32), 256, 0, stream>>>(x, corr_w, corr_b, tm);
  score_kernel<<<dim3(98, 28), 256, 0, stream>>>(tm, m0);
  conv_kernel<3, 5, 28, 8, true, false>
      <<<dim3(8, 28), 256, (600 + 784) * 4, stream>>>(m0, mw1, mb1, m1, 64);
  conv_kernel<64, 3, 26, 8, true, true>
      <<<dim3(16, 28), 256, (4608 + 676) * 4, stream>>>(m1, mw2, mb2, m2, 128);
  conv_kernel<128, 3, 26, 8, true, true>
      <<<dim3(16, 28), 256, (9216 + 676) * 4, stream>>>(m2, mw3, mb3, m3, 128);
  conv_kernel<128, 3, 26, 8, false, true>
      <<<dim3(32, 28), 256, (9216 + 676) * 4, stream>>>(m3, mw4, mb4, m4, 256);
  final_reduce_kernel<<<dim3(1024), 256, 0, stream>>>(x, m4, rr);
  linear_kernel<<<dim3(4), 256, 0, stream>>>(rr, lin_w, lin_b, out);
}

// Round 2
// 426.186 us; speedup vs baseline: 2.5479x; 2.5479x over previous
//
#include <hip/hip_runtime.h>

// Shapes: x[4][256][8][28][28] fp32. b = n*7+t in [0,28) for conv stages.
// tm  [32 nt][128][784] fp32
// m0  [28][3][784] fp32                  (relu(sim))
// m1  [28][784][64]  bf16 padded ch-last (conv1 out; border rows/cols zero)
// m2  [28][784][128] bf16 padded ch-last
// m3  [28][784][128] bf16 padded ch-last
// m4  [28][256][676] fp32                (conv4 out)
// out [4][256] fp32

#define NORM_INV 0.07978845608028654f   // 1/(sqrt(2*pi)*5)

typedef __attribute__((ext_vector_type(8))) short bf16x8;
typedef __attribute__((ext_vector_type(4))) float f32x4;

__device__ inline ushort f2bf(float v) {
  union { float f; uint u; } c; c.f = v;
  const uint u = c.u + 0x7FFFu + ((c.u >> 16) & 1u);   // RNE
  return (ushort)(u >> 16);
}

// ---------------------------------------------------------------------------
// Kernel A: tm[nt][o][hw] = sum_k corr_w[o][k]*relu(x[n][k][t][hw]) + corr_b[o]
// ---------------------------------------------------------------------------
__global__ __launch_bounds__(256) void tm_kernel(const float* __restrict__ x,
    const float* __restrict__ cw, const float* __restrict__ cb,
    float* __restrict__ tm) {
  const int tid = threadIdx.x;
  const int p = blockIdx.x * 256 + tid;
  const int c0 = blockIdx.y * 32;
  const int nt = blockIdx.z;
  const int n = nt >> 3, t = nt & 7;
  __shared__ float wl[256 * 32];
  for (int idx = tid; idx < 256 * 32; idx += 256) {
    const int cc = idx & 31, k = idx >> 5;
    wl[idx] = cw[(c0 + cc) * 256 + k];
  }
  __syncthreads();
  if (p >= 784) return;
  float acc[32];
#pragma unroll
  for (int i = 0; i < 32; ++i) acc[i] = 0.f;
  const float* xp = x + ((size_t)n * 2048 + t) * 784 + p;
#pragma unroll 4
  for (int k = 0; k < 256; ++k) {
    const float xv = fmaxf(xp[(size_t)k * 6272], 0.f);
    const float* w = &wl[k * 32];
#pragma unroll
    for (int c4 = 0; c4 < 32; c4 += 4) {
      const float4 wv = *(const float4*)&w[c4];
      acc[c4 + 0] += wv.x * xv; acc[c4 + 1] += wv.y * xv;
      acc[c4 + 2] += wv.z * xv; acc[c4 + 3] += wv.w * xv;
    }
  }
  float* op = tm + ((size_t)nt * 128 + c0) * 784 + p;
#pragma unroll
  for (int cc = 0; cc < 32; ++cc) op[(size_t)cc * 784] = acc[cc] + cb[c0 + cc];
}

// ---------------------------------------------------------------------------
// Kernel B: fused score GEMM + argmax + double softmax -> relu(sim) = m0
// ---------------------------------------------------------------------------
__global__ __launch_bounds__(256) void score_kernel(const float* __restrict__ tm,
    float* __restrict__ m0) {
  const int tid = threadIdx.x;
  const int nt = blockIdx.y;
  const int n = nt / 7, t = nt % 7;
  const int uv0 = blockIdx.x * 8;
  const float* Ap = tm + (size_t)(n * 8 + t) * 128 * 784;
  const float* Bp = tm + (size_t)(n * 8 + t + 1) * 128 * 784;
  __shared__ float Al[128 * 8];
  __shared__ float sc[8 * 784];
  for (int idx = tid; idx < 1024; idx += 256) {
    const int u = idx & 7, c = idx >> 3;
    Al[idx] = Ap[c * 784 + uv0 + u];
  }
  __syncthreads();
  float acc[8][4];
#pragma unroll
  for (int u = 0; u < 8; ++u)
#pragma unroll
    for (int j = 0; j < 4; ++j) acc[u][j] = 0.f;
  const bool v3 = tid < 16;
  for (int c = 0; c < 128; ++c) {
    const float4 a0 = *(const float4*)&Al[c * 8];
    const float4 a1 = *(const float4*)&Al[c * 8 + 4];
    const float av[8] = {a0.x, a0.y, a0.z, a0.w, a1.x, a1.y, a1.z, a1.w};
    const float* bp = &Bp[c * 784 + tid];
    float bcv[4];
    bcv[0] = bp[0]; bcv[1] = bp[256]; bcv[2] = bp[512];
    bcv[3] = v3 ? bp[768] : 0.f;
#pragma unroll
    for (int u = 0; u < 8; ++u)
#pragma unroll
      for (int j = 0; j < 4; ++j) acc[u][j] += av[u] * bcv[j];
  }
#pragma unroll
  for (int u = 0; u < 8; ++u) {
    sc[u * 784 + tid] = acc[u][0];
    sc[u * 784 + tid + 256] = acc[u][1];
    sc[u * 784 + tid + 512] = acc[u][2];
    if (v3) sc[u * 784 + tid + 768] = acc[u][3];
  }
  __syncthreads();
  const int r = tid >> 5, l = tid & 31;
  const float* row = &sc[r * 784];
  float bv = -1e30f; int bi = 0;
  for (int a2 = l; a2 < 784; a2 += 32) {
    const float v = row[a2];
    if (v > bv) { bv = v; bi = a2; }
  }
#pragma unroll
  for (int off = 16; off; off >>= 1) {
    const float ov = __shfl_xor(bv, off, 32);
    const int oi = __shfl_xor(bi, off, 32);
    if (ov > bv || (ov == bv && oi < bi)) { bv = ov; bi = oi; }
  }
  const int ast = bi / 28;
  const int bst = bi - ast * 28;
  float mx = -1e30f, my = -1e30f;
  for (int a2 = l; a2 < 784; a2 += 32) {
    const float v = row[a2];
    const int a = a2 / 28; const int bb = a2 - a * 28;
    const float gx = __expf((float)(a - ast) * 0.04f) * NORM_INV;
    const float gy = __expf((float)(bb - bst) * 0.04f) * NORM_INV;
    mx = fmaxf(mx, gx * v); my = fmaxf(my, gy * v);
  }
#pragma unroll
  for (int off = 16; off; off >>= 1) {
    mx = fmaxf(mx, __shfl_xor(mx, off, 32));
    my = fmaxf(my, __shfl_xor(my, off, 32));
  }
  float sx = 0.f, sxw = 0.f, sy = 0.f, syw = 0.f;
  for (int a2 = l; a2 < 784; a2 += 32) {
    const float v = row[a2];
    const int a = a2 / 28; const int bb = a2 - a * 28;
    const float gx = __expf((float)(a - ast) * 0.04f) * NORM_INV;
    const float gy = __expf((float)(bb - bst) * 0.04f) * NORM_INV;
    const float ex = __expf((gx * v - mx) * 100.f);
    const float ey = __expf((gy * v - my) * 100.f);
    sx += ex; sxw += (float)a * ex;
    sy += ey; syw += (float)bb * ey;
  }
#pragma unroll
  for (int off = 16; off; off >>= 1) {
    sx += __shfl_xor(sx, off, 32); sxw += __shfl_xor(sxw, off, 32);
    sy += __shfl_xor(sy, off, 32); syw += __shfl_xor(syw, off, 32);
  }
  if (l == 0) {
    const int uv = uv0 + r;
    float* op = m0 + (size_t)nt * 3 * 784 + uv;
    op[0]    = fmaxf(sxw / sx, 0.f);
    op[784]  = fmaxf(syw / sy, 0.f);
    op[1568] = fmaxf(bv, 0.f);
  }
}

// ---------------------------------------------------------------------------
// conv1: 3 -> 64, K=5, 28x28 -> 26x26, fp32 direct; writes bf16 padded
// channel-last m1[b][784][64]. grid (4 co-tiles of 16, 28 b), 256 thr.
// ---------------------------------------------------------------------------
__global__ __launch_bounds__(256) void conv1_kernel(const float* __restrict__ m0,
    const float* __restrict__ w, const float* __restrict__ bias,
    ushort* __restrict__ out) {
  const int b = blockIdx.y;
  const int co0 = blockIdx.x * 16;
  const int tid = threadIdx.x;
  __shared__ float il[3 * 784];
  __shared__ float wl[75 * 16];          // [ci*25+tap][c]
  const float* ip = m0 + (size_t)b * 2352;
  for (int i = tid; i < 2352; i += 256) il[i] = ip[i];
  for (int i = tid; i < 1200; i += 256) {
    const int c = i & 15, rest = i >> 4;
    wl[i] = w[(size_t)(co0 + c) * 75 + rest];
  }
  __syncthreads();
  float acc[3][16];
#pragma unroll
  for (int pg = 0; pg < 3; ++pg)
#pragma unroll
    for (int c = 0; c < 16; ++c) acc[pg][c] = 0.f;
  int pys[3], pxs[3];
#pragma unroll
  for (int pg = 0; pg < 3; ++pg) {
    const int pix = pg * 256 + tid;
    pys[pg] = pix / 26; pxs[pg] = pix - pys[pg] * 26;
  }
  for (int ci = 0; ci < 3; ++ci) {
#pragma unroll
    for (int pg = 0; pg < 3; ++pg) {
      if (pg * 256 + tid >= 676) break;
#pragma unroll
      for (int dy = 0; dy < 5; ++dy) {
        const int iy = pys[pg] + dy - 1;
        if ((unsigned)iy >= 28u) continue;
#pragma unroll
        for (int dx = 0; dx < 5; ++dx) {
          const int ix = pxs[pg] + dx - 1;
          if ((unsigned)ix >= 28u) continue;
          const float v = il[ci * 784 + iy * 28 + ix];
          const float* wp = &wl[(ci * 25 + dy * 5 + dx) * 16];
#pragma unroll
          for (int c4 = 0; c4 < 16; c4 += 4) {
            const float4 wv = *(const float4*)&wp[c4];
            acc[pg][c4 + 0] += wv.x * v; acc[pg][c4 + 1] += wv.y * v;
            acc[pg][c4 + 2] += wv.z * v; acc[pg][c4 + 3] += wv.w * v;
          }
        }
      }
    }
  }
#pragma unroll
  for (int pg = 0; pg < 3; ++pg) {
    const int pix = pg * 256 + tid;
    if (pix >= 676) break;
    const int ipo = (pys[pg] + 1) * 28 + pxs[pg] + 1;
    ushort* op = out + ((size_t)b * 784 + ipo) * 64 + co0;
#pragma unroll
    for (int c = 0; c < 16; ++c)
      op[c] = f2bf(fmaxf(acc[pg][c] + bias[co0 + c], 0.f));
  }
}

// ---------------------------------------------------------------------------
// Weight pack: mw [COUT][CIN][3][3] fp32 -> Bp [kc][n16][lane][8] bf16,
// k = tap*CIN + ci (so a K=32 chunk has one tap and 32 consecutive ci).
// ---------------------------------------------------------------------------
__global__ __launch_bounds__(256) void pack_w_kernel(const float* __restrict__ w,
    ushort* __restrict__ Bp, int CIN, int N16, int total) {
  const int idx = blockIdx.x * 256 + threadIdx.x;
  if (idx >= total) return;
  const int j = idx & 7;
  const int l = (idx >> 3) & 63;
  const int rest = idx >> 9;
  const int n16 = rest % N16;
  const int kc = rest / N16;
  const int co = n16 * 16 + (l & 15);
  const int kk = kc * 32 + (l >> 4) * 8 + j;
  const int tap = kk / CIN;
  const int ci = kk - tap * CIN;
  Bp[idx] = f2bf(w[((size_t)co * CIN + ci) * 9 + tap]);
}

// ---------------------------------------------------------------------------
// MFMA implicit-GEMM conv (K=3, pad=1, 26x26 out on 28x28 padded ch-last in).
// Block = 128 thr = 2 waves (M-stacked). Wave tile 64 pix x 64 cout.
// A-frags: 16B loads from padded ch-last input (no boundary checks).
// B-frags: coalesced loads from pre-packed weights. No LDS, no barriers.
// grid (6 Mtiles, 28 b, COUT/64).
// ---------------------------------------------------------------------------
template<int CIN, bool FINAL>
__global__ __launch_bounds__(128) void conv_mfma_kernel(
    const ushort* __restrict__ in, const ushort* __restrict__ Bp,
    const float* __restrict__ bias, ushort* __restrict__ outp,
    float* __restrict__ outf, int COUTC) {
  constexpr int KC = CIN * 9 / 32;       // 18 or 36 (even)
  constexpr int CPG = CIN / 32;          // chunks per tap
  const int N16 = COUTC >> 4;
  const int tid = threadIdx.x;
  const int l = tid & 63;
  const int wm = tid >> 6;
  const int b = blockIdx.y;
  const int p0 = blockIdx.x * 128 + wm * 64;
  const int n0 = blockIdx.z * 64;
  const int lr = l & 15, lq = l >> 4;
  int ipb[4];
#pragma unroll
  for (int mf = 0; mf < 4; ++mf) {
    int p = p0 + mf * 16 + lr;
    if (p > 675) p = 675;                // clamp; masked at store
    ipb[mf] = p + 2 * (p / 26);          // padded index at (dy,dx)=(0,0)
  }
  const ushort* inb = in + (size_t)b * 784 * CIN;
  f32x4 acc[4][4];
#pragma unroll
  for (int mf = 0; mf < 4; ++mf)
#pragma unroll
    for (int nf = 0; nf < 4; ++nf) {
      f32x4 z = {0.f, 0.f, 0.f, 0.f};
      acc[mf][nf] = z;
    }

  auto loadA = [&](int kc, bf16x8* a) {
    const int tap = kc / CPG;
    const int ci0 = (kc - tap * CPG) * 32 + lq * 8;
    const int off = (tap / 3) * 28 + (tap - (tap / 3) * 3);
#pragma unroll
    for (int mf = 0; mf < 4; ++mf)
      a[mf] = *(const bf16x8*)(inb + (size_t)(ipb[mf] + off) * CIN + ci0);
  };
  auto loadB = [&](int kc, bf16x8* bb) {
    const ushort* bp = Bp + (((size_t)kc * N16 + (n0 >> 4)) * 64 + l) * 8;
#pragma unroll
    for (int nf = 0; nf < 4; ++nf)
      bb[nf] = *(const bf16x8*)(bp + (size_t)nf * 512);
  };
  auto domfma = [&](bf16x8* a, bf16x8* bb) {
#pragma unroll
    for (int mf = 0; mf < 4; ++mf)
#pragma unroll
      for (int nf = 0; nf < 4; ++nf)
        acc[mf][nf] = __builtin_amdgcn_mfma_f32_16x16x32_bf16(
            a[mf], bb[nf], acc[mf][nf], 0, 0, 0);
  };

  bf16x8 aA[4], bA[4], aB[4], bB[4];
  loadA(0, aA); loadB(0, bA);
  for (int kc = 0; kc < KC; kc += 2) {
    loadA(kc + 1, aB); loadB(kc + 1, bB);
    domfma(aA, bA);
    if (kc + 2 < KC) { loadA(kc + 2, aA); loadB(kc + 2, bA); }
    domfma(aB, bB);
  }
  // epilogue: D col(lane&15)=cout, row((lane>>4)*4+reg)=pixel
#pragma unroll
  for (int nf = 0; nf < 4; ++nf) {
    const int co = n0 + nf * 16 + lr;
    const float bv = bias[co];
#pragma unroll
    for (int mf = 0; mf < 4; ++mf) {
#pragma unroll
      for (int r = 0; r < 4; ++r) {
        const int p = p0 + mf * 16 + lq * 4 + r;
        if (p < 676) {
          const float v = acc[mf][nf][r] + bv;
          if constexpr (FINAL) {
            outf[((size_t)b * COUTC + co) * 676 + p] = v;
          } else {
            const int ipo = p + 2 * (p / 26) + 29;
            outp[((size_t)b * 784 + ipo) * COUTC + co] = f2bf(fmaxf(v, 0.f));
          }
        }
      }
    }
  }
}

// ---------------------------------------------------------------------------
// D1: r[n][c] = relu( mean_thw(x) + mean_t,hw(m4) )
// ---------------------------------------------------------------------------
__global__ __launch_bounds__(256) void final_reduce_kernel(const float* __restrict__ x,
    const float* __restrict__ m4, float* __restrict__ r) {
  const int nc = blockIdx.x;
  const int n = nc >> 8, c = nc & 255;
  const int tid = threadIdx.x;
  const float* xs = x + (size_t)nc * 6272;
  float s = 0.f;
  for (int i = tid; i < 6272; i += 256) s += xs[i];
  float s2 = 0.f;
  for (int t = 0; t < 7; ++t) {
    const float* ms = m4 + ((size_t)(n * 7 + t) * 256 + c) * 676;
    for (int i = tid; i < 676; i += 256) s2 += ms[i];
  }
  float v = s * (1.f / 6272.f) + s2 * (1.f / 4732.f);
#pragma unroll
  for (int off = 32; off; off >>= 1) v += __shfl_down(v, off);
  __shared__ float red[4];
  if ((tid & 63) == 0) red[tid >> 6] = v;
  __syncthreads();
  if (tid == 0) r[nc] = fmaxf(red[0] + red[1] + red[2] + red[3], 0.f);
}

__global__ __launch_bounds__(256) void linear_kernel(const float* __restrict__ r,
    const float* __restrict__ lw, const float* __restrict__ lb,
    float* __restrict__ out) {
  const int n = blockIdx.x;
  const int j = threadIdx.x;
  __shared__ float rl[256];
  rl[j] = r[n * 256 + j];
  __syncthreads();
  float acc = lb[j];
  const float* w = lw + (size_t)j * 256;
#pragma unroll 4
  for (int c = 0; c < 256; c += 4) {
    const float4 wv = *(const float4*)&w[c];
    acc += wv.x * rl[c] + wv.y * rl[c + 1] + wv.z * rl[c + 2] + wv.w * rl[c + 3];
  }
  out[n * 256 + j] = acc;
}

extern "C" void kernel_launch(void* const* d_in, const int* in_sizes, int n_in,
                              void* d_out, int out_size, void* d_ws, size_t ws_size,
                              hipStream_t stream) {
  const float* x      = (const float*)d_in[0];
  const float* corr_w = (const float*)d_in[1];
  const float* corr_b = (const float*)d_in[2];
  const float* mw1 = (const float*)d_in[3];
  const float* mb1 = (const float*)d_in[4];
  const float* mw2 = (const float*)d_in[5];
  const float* mb2 = (const float*)d_in[6];
  const float* mw3 = (const float*)d_in[7];
  const float* mb3 = (const float*)d_in[8];
  const float* mw4 = (const float*)d_in[9];
  const float* mb4 = (const float*)d_in[10];
  const float* lin_w = (const float*)d_in[11];
  const float* lin_b = (const float*)d_in[12];
  float* out = (float*)d_out;
  char* wsb = (char*)d_ws;

  // byte-offset workspace map (34.74 MB total; tm and m4 time-share [0,...))
  float*  tm  = (float*)(wsb + 0);           // 12,845,056 B (dead after score)
  float*  m4  = (float*)(wsb + 0);           // 19,382,272 B (written by conv4)
  float*  m0  = (float*)(wsb + 19382272);    //    263,424 B
  float*  rr  = (float*)(wsb + 19645696);    //      4,096 B
  ushort* m1  = (ushort*)(wsb + 19649792);   //  2,809,856 B bf16 padded
  ushort* m2  = (ushort*)(wsb + 22459648);   //  5,619,712 B
  ushort* m3  = (ushort*)(wsb + 28079360);   //  5,619,712 B
  ushort* Bp2 = (ushort*)(wsb + 33699072);   //    147,456 B
  ushort* Bp3 = (ushort*)(wsb + 33846528);   //    294,912 B
  ushort* Bp4 = (ushort*)(wsb + 34141440);   //    589,824 B

  // zero padded activation buffers (borders must be 0 for the halo loads)
  hipMemsetAsync(m1, 0, 2809856, stream);
  hipMemsetAsync(m2, 0, 5619712, stream);
  hipMemsetAsync(m3, 0, 5619712, stream);

  pack_w_kernel<<<dim3(288), 256, 0, stream>>>(mw2, Bp2, 64, 8, 73728);
  pack_w_kernel<<<dim3(576), 256, 0, stream>>>(mw3, Bp3, 128, 8, 147456);
  pack_w_kernel<<<dim3(1152), 256, 0, stream>>>(mw4, Bp4, 128, 16, 294912);

  tm_kernel<<<dim3(4, 4, 32), 256, 0, stream>>>(x, corr_w, corr_b, tm);
  score_kernel<<<dim3(98, 28), 256, 0, stream>>>(tm, m0);
  conv1_kernel<<<dim3(4, 28), 256, 0, stream>>>(m0, mw1, mb1, m1);
  conv_mfma_kernel<64, false><<<dim3(6, 28, 2), 128, 0, stream>>>(
      m1, Bp2, mb2, m2, nullptr, 128);
  conv_mfma_kernel<128, false><<<dim3(6, 28, 2), 128, 0, stream>>>(
      m2, Bp3, mb3, m3, nullptr, 128);
  conv_mfma_kernel<128, true><<<dim3(6, 28, 4), 128, 0, stream>>>(
      m3, Bp4, mb4, nullptr, m4, 256);
  final_reduce_kernel<<<dim3(1024), 256, 0, stream>>>(x, m4, rr);
  linear_kernel<<<dim3(4), 256, 0, stream>>>(rr, lin_w, lin_b, out);
}

// Round 4
// 355.554 us; speedup vs baseline: 3.0540x; 1.1987x over previous
//
#include <hip/hip_runtime.h>

// Shapes: x[4][256][8][28][28] fp32. b = n*7+t in [0,28) for conv stages.
// tm_t [32 nt][784][128] bf16 channel-last   (corr-projected relu'd input)
// m0  [28][3][784] fp32                  (relu(sim))
// m1  [28][784][64]  bf16 padded ch-last (conv1 out; border rows/cols zero)
// m2  [28][784][128] bf16 padded ch-last
// m3  [28][784][128] bf16 padded ch-last
// m4  [28][256][676] fp32                (conv4 out)
// out [4][256] fp32

#define NORM_INV 0.07978845608028654f   // 1/(sqrt(2*pi)*5)

typedef __attribute__((ext_vector_type(8))) short bf16x8;
typedef __attribute__((ext_vector_type(4))) float f32x4;

__device__ inline ushort f2bf(float v) {
  union { float f; uint u; } c; c.f = v;
  const uint u = c.u + 0x7FFFu + ((c.u >> 16) & 1u);   // RNE
  return (ushort)(u >> 16);
}

// ---------------------------------------------------------------------------
// Kernel A: tm_t[nt][hw][o] = bf16( sum_k cw[o][k]*relu(x[n][k][t][hw]) + cb[o] )
// grid (4 pixel tiles, 4 c-chunks of 32, 32 nt), 256 threads
// ---------------------------------------------------------------------------
__global__ __launch_bounds__(256) void tm_kernel(const float* __restrict__ x,
    const float* __restrict__ cw, const float* __restrict__ cb,
    ushort* __restrict__ tmt) {
  const int tid = threadIdx.x;
  const int p = blockIdx.x * 256 + tid;
  const int c0 = blockIdx.y * 32;
  const int nt = blockIdx.z;
  const int n = nt >> 3, t = nt & 7;
  __shared__ float wl[256 * 32];
  for (int idx = tid; idx < 256 * 32; idx += 256) {
    const int cc = idx & 31, k = idx >> 5;
    wl[idx] = cw[(c0 + cc) * 256 + k];
  }
  __syncthreads();
  if (p >= 784) return;
  float acc[32];
#pragma unroll
  for (int i = 0; i < 32; ++i) acc[i] = 0.f;
  const float* xp = x + ((size_t)n * 2048 + t) * 784 + p;
#pragma unroll 4
  for (int k = 0; k < 256; ++k) {
    const float xv = fmaxf(xp[(size_t)k * 6272], 0.f);
    const float* w = &wl[k * 32];
#pragma unroll
    for (int c4 = 0; c4 < 32; c4 += 4) {
      const float4 wv = *(const float4*)&w[c4];
      acc[c4 + 0] += wv.x * xv; acc[c4 + 1] += wv.y * xv;
      acc[c4 + 2] += wv.z * xv; acc[c4 + 3] += wv.w * xv;
    }
  }
  ushort* op = tmt + ((size_t)nt * 784 + p) * 128 + c0;
#pragma unroll
  for (int q = 0; q < 4; ++q) {
    union { ushort u[8]; bf16x8 v; } pk;
#pragma unroll
    for (int j = 0; j < 8; ++j)
      pk.u[j] = f2bf(acc[q * 8 + j] + cb[c0 + q * 8 + j]);
    *(bf16x8*)(op + q * 8) = pk.v;
  }
}

// ---------------------------------------------------------------------------
// Kernel B: MFMA score GEMM (16 uv x 784 ab, K=128) + argmax + double softmax.
// Both MFMA operands read channel-last tm_t directly (16B frags, no staging).
// grid (49 uv-tiles, 28 nt), 256 threads = 4 waves (ab-interleaved).
// ---------------------------------------------------------------------------
__global__ __launch_bounds__(256) void score_kernel(const ushort* __restrict__ tmt,
    float* __restrict__ m0) {
  const int tid = threadIdx.x;
  const int nt = blockIdx.y;
  const int n = nt / 7, t = nt % 7;
  const int uv0 = blockIdx.x * 16;
  const ushort* bfp = tmt + (size_t)(n * 8 + t) * 784 * 128;      // frame t
  const ushort* bhp = tmt + (size_t)(n * 8 + t + 1) * 784 * 128;  // frame t+1
  __shared__ float sc[16 * 785];             // score tile [uv][ab], +1 pad
  __shared__ float gt[16 * 64];              // per-row gaussian tables
  const int w = tid >> 6;
  const int l = tid & 63;
  const int lr = l & 15, lq = l >> 4;
  // A-fragments: frame-t pixel uv0+lr, k-chunks of 32
  bf16x8 af[4];
#pragma unroll
  for (int kc = 0; kc < 4; ++kc)
    af[kc] = *(const bf16x8*)(bfp + (uv0 + lr) * 128 + kc * 32 + lq * 8);
  f32x4 acc[13];
#pragma unroll
  for (int i = 0; i < 13; ++i) { f32x4 z = {0.f,0.f,0.f,0.f}; acc[i] = z; }
#pragma unroll
  for (int i = 0; i < 13; ++i) {
    const int nf = i * 4 + w;
    if (nf < 49) {
      const ushort* bp = bhp + (nf * 16 + lr) * 128 + lq * 8;
      const bf16x8 b0 = *(const bf16x8*)(bp);
      const bf16x8 b1 = *(const bf16x8*)(bp + 32);
      const bf16x8 b2 = *(const bf16x8*)(bp + 64);
      const bf16x8 b3 = *(const bf16x8*)(bp + 96);
      acc[i] = __builtin_amdgcn_mfma_f32_16x16x32_bf16(af[0], b0, acc[i], 0, 0, 0);
      acc[i] = __builtin_amdgcn_mfma_f32_16x16x32_bf16(af[1], b1, acc[i], 0, 0, 0);
      acc[i] = __builtin_amdgcn_mfma_f32_16x16x32_bf16(af[2], b2, acc[i], 0, 0, 0);
      acc[i] = __builtin_amdgcn_mfma_f32_16x16x32_bf16(af[3], b3, acc[i], 0, 0, 0);
    }
  }
  // D: row(uv_local) = lq*4+r, col(ab_local) = lr
#pragma unroll
  for (int i = 0; i < 13; ++i) {
    const int nf = i * 4 + w;
    if (nf < 49) {
#pragma unroll
      for (int r = 0; r < 4; ++r)
        sc[(lq * 4 + r) * 785 + nf * 16 + lr] = acc[i][r];
    }
  }
  __syncthreads();
  // ---- softmax phase: 16 lanes per uv row
  const int row = tid >> 4, l16 = tid & 15;
  const float* rowp = &sc[row * 785];
  float bv = -1e30f; int bi = 0;
#pragma unroll 7
  for (int i = 0; i < 49; ++i) {
    const int a2 = i * 16 + l16;
    const float v = rowp[a2];
    if (v > bv) { bv = v; bi = a2; }
  }
#pragma unroll
  for (int off = 8; off; off >>= 1) {
    const float ov = __shfl_xor(bv, off, 16);
    const int oi = __shfl_xor(bi, off, 16);
    if (ov > bv || (ov == bv && oi < bi)) { bv = ov; bi = oi; }
  }
  const int ast = bi / 28;
  const int bst = bi - ast * 28;
  float* g = &gt[row * 64];
  for (int q = l16; q < 28; q += 16) {
    g[q]      = __expf((float)(q - ast) * 0.04f) * NORM_INV;
    g[32 + q] = __expf((float)(q - bst) * 0.04f) * NORM_INV;
  }
  float mx = -1e30f, my = -1e30f;
#pragma unroll 7
  for (int i = 0; i < 49; ++i) {
    const int a2 = i * 16 + l16;
    const float v = rowp[a2];
    const int a = a2 / 28; const int bb = a2 - a * 28;
    mx = fmaxf(mx, g[a] * v); my = fmaxf(my, g[32 + bb] * v);
  }
#pragma unroll
  for (int off = 8; off; off >>= 1) {
    mx = fmaxf(mx, __shfl_xor(mx, off, 16));
    my = fmaxf(my, __shfl_xor(my, off, 16));
  }
  float sx = 0.f, sxw = 0.f, sy = 0.f, syw = 0.f;
#pragma unroll 7
  for (int i = 0; i < 49; ++i) {
    const int a2 = i * 16 + l16;
    const float v = rowp[a2];
    const int a = a2 / 28; const int bb = a2 - a * 28;
    const float ex = __expf((g[a] * v - mx) * 100.f);
    const float ey = __expf((g[32 + bb] * v - my) * 100.f);
    sx += ex; sxw += (float)a * ex;
    sy += ey; syw += (float)bb * ey;
  }
#pragma unroll
  for (int off = 8; off; off >>= 1) {
    sx += __shfl_xor(sx, off, 16); sxw += __shfl_xor(sxw, off, 16);
    sy += __shfl_xor(sy, off, 16); syw += __shfl_xor(syw, off, 16);
  }
  if (l16 == 0) {
    const int uv = uv0 + row;
    float* op = m0 + (size_t)nt * 3 * 784 + uv;
    op[0]    = fmaxf(sxw / sx, 0.f);
    op[784]  = fmaxf(syw / sy, 0.f);
    op[1568] = fmaxf(bv, 0.f);
  }
}

// ---------------------------------------------------------------------------
// conv1: 3 -> 64, K=5, 28x28 -> 26x26, fp32 direct; writes bf16 padded
// channel-last m1[b][784][64]. grid (4 co-tiles of 16, 28 b), 256 thr.
// ---------------------------------------------------------------------------
__global__ __launch_bounds__(256) void conv1_kernel(const float* __restrict__ m0,
    const float* __restrict__ w, const float* __restrict__ bias,
    ushort* __restrict__ out) {
  const int b = blockIdx.y;
  const int co0 = blockIdx.x * 16;
  const int tid = threadIdx.x;
  __shared__ float il[3 * 784];
  __shared__ float wl[75 * 16];          // [ci*25+tap][c]
  const float* ip = m0 + (size_t)b * 2352;
  for (int i = tid; i < 2352; i += 256) il[i] = ip[i];
  for (int i = tid; i < 1200; i += 256) {
    const int c = i & 15, rest = i >> 4;
    wl[i] = w[(size_t)(co0 + c) * 75 + rest];
  }
  __syncthreads();
  float acc[3][16];
#pragma unroll
  for (int pg = 0; pg < 3; ++pg)
#pragma unroll
    for (int c = 0; c < 16; ++c) acc[pg][c] = 0.f;
  int pys[3], pxs[3];
#pragma unroll
  for (int pg = 0; pg < 3; ++pg) {
    const int pix = pg * 256 + tid;
    pys[pg] = pix / 26; pxs[pg] = pix - pys[pg] * 26;
  }
  for (int ci = 0; ci < 3; ++ci) {
#pragma unroll
    for (int pg = 0; pg < 3; ++pg) {
      if (pg * 256 + tid >= 676) break;
#pragma unroll
      for (int dy = 0; dy < 5; ++dy) {
        const int iy = pys[pg] + dy - 1;
        if ((unsigned)iy >= 28u) continue;
#pragma unroll
        for (int dx = 0; dx < 5; ++dx) {
          const int ix = pxs[pg] + dx - 1;
          if ((unsigned)ix >= 28u) continue;
          const float v = il[ci * 784 + iy * 28 + ix];
          const float* wp = &wl[(ci * 25 + dy * 5 + dx) * 16];
#pragma unroll
          for (int c4 = 0; c4 < 16; c4 += 4) {
            const float4 wv = *(const float4*)&wp[c4];
            acc[pg][c4 + 0] += wv.x * v; acc[pg][c4 + 1] += wv.y * v;
            acc[pg][c4 + 2] += wv.z * v; acc[pg][c4 + 3] += wv.w * v;
          }
        }
      }
    }
  }
#pragma unroll
  for (int pg = 0; pg < 3; ++pg) {
    const int pix = pg * 256 + tid;
    if (pix >= 676) break;
    const int ipo = (pys[pg] + 1) * 28 + pxs[pg] + 1;
    ushort* op = out + ((size_t)b * 784 + ipo) * 64 + co0;
#pragma unroll
    for (int c = 0; c < 16; ++c)
      op[c] = f2bf(fmaxf(acc[pg][c] + bias[co0 + c], 0.f));
  }
}

// ---------------------------------------------------------------------------
// Weight pack: mw [COUT][CIN][3][3] fp32 -> Bp [kc][n16][lane][8] bf16,
// k = tap*CIN + ci.
// ---------------------------------------------------------------------------
__global__ __launch_bounds__(256) void pack_w_kernel(const float* __restrict__ w,
    ushort* __restrict__ Bp, int CIN, int N16, int total) {
  const int idx = blockIdx.x * 256 + threadIdx.x;
  if (idx >= total) return;
  const int j = idx & 7;
  const int l = (idx >> 3) & 63;
  const int rest = idx >> 9;
  const int n16 = rest % N16;
  const int kc = rest / N16;
  const int co = n16 * 16 + (l & 15);
  const int kk = kc * 32 + (l >> 4) * 8 + j;
  const int tap = kk / CIN;
  const int ci = kk - tap * CIN;
  Bp[idx] = f2bf(w[((size_t)co * CIN + ci) * 9 + tap]);
}

// ---------------------------------------------------------------------------
// MFMA implicit-GEMM conv (K=3, pad=1, 26x26 out on 28x28 padded ch-last in).
// ---------------------------------------------------------------------------
template<int CIN, bool FINAL>
__global__ __launch_bounds__(128) void conv_mfma_kernel(
    const ushort* __restrict__ in, const ushort* __restrict__ Bp,
    const float* __restrict__ bias, ushort* __restrict__ outp,
    float* __restrict__ outf, int COUTC) {
  constexpr int KC = CIN * 9 / 32;
  constexpr int CPG = CIN / 32;
  const int N16 = COUTC >> 4;
  const int tid = threadIdx.x;
  const int l = tid & 63;
  const int wm = tid >> 6;
  const int b = blockIdx.y;
  const int p0 = blockIdx.x * 128 + wm * 64;
  const int n0 = blockIdx.z * 64;
  const int lr = l & 15, lq = l >> 4;
  int ipb[4];
#pragma unroll
  for (int mf = 0; mf < 4; ++mf) {
    int p = p0 + mf * 16 + lr;
    if (p > 675) p = 675;
    ipb[mf] = p + 2 * (p / 26);
  }
  const ushort* inb = in + (size_t)b * 784 * CIN;
  f32x4 acc[4][4];
#pragma unroll
  for (int mf = 0; mf < 4; ++mf)
#pragma unroll
    for (int nf = 0; nf < 4; ++nf) {
      f32x4 z = {0.f, 0.f, 0.f, 0.f};
      acc[mf][nf] = z;
    }

  auto loadA = [&](int kc, bf16x8* a) {
    const int tap = kc / CPG;
    const int ci0 = (kc - tap * CPG) * 32 + lq * 8;
    const int off = (tap / 3) * 28 + (tap - (tap / 3) * 3);
#pragma unroll
    for (int mf = 0; mf < 4; ++mf)
      a[mf] = *(const bf16x8*)(inb + (size_t)(ipb[mf] + off) * CIN + ci0);
  };
  auto loadB = [&](int kc, bf16x8* bb) {
    const ushort* bp = Bp + (((size_t)kc * N16 + (n0 >> 4)) * 64 + l) * 8;
#pragma unroll
    for (int nf = 0; nf < 4; ++nf)
      bb[nf] = *(const bf16x8*)(bp + (size_t)nf * 512);
  };
  auto domfma = [&](bf16x8* a, bf16x8* bb) {
#pragma unroll
    for (int mf = 0; mf < 4; ++mf)
#pragma unroll
      for (int nf = 0; nf < 4; ++nf)
        acc[mf][nf] = __builtin_amdgcn_mfma_f32_16x16x32_bf16(
            a[mf], bb[nf], acc[mf][nf], 0, 0, 0);
  };

  bf16x8 aA[4], bA[4], aB[4], bB[4];
  loadA(0, aA); loadB(0, bA);
  for (int kc = 0; kc < KC; kc += 2) {
    loadA(kc + 1, aB); loadB(kc + 1, bB);
    domfma(aA, bA);
    if (kc + 2 < KC) { loadA(kc + 2, aA); loadB(kc + 2, bA); }
    domfma(aB, bB);
  }
#pragma unroll
  for (int nf = 0; nf < 4; ++nf) {
    const int co = n0 + nf * 16 + lr;
    const float bv = bias[co];
#pragma unroll
    for (int mf = 0; mf < 4; ++mf) {
#pragma unroll
      for (int r = 0; r < 4; ++r) {
        const int p = p0 + mf * 16 + lq * 4 + r;
        if (p < 676) {
          const float v = acc[mf][nf][r] + bv;
          if constexpr (FINAL) {
            outf[((size_t)b * COUTC + co) * 676 + p] = v;
          } else {
            const int ipo = p + 2 * (p / 26) + 29;
            outp[((size_t)b * 784 + ipo) * COUTC + co] = f2bf(fmaxf(v, 0.f));
          }
        }
      }
    }
  }
}

// ---------------------------------------------------------------------------
// D1: r[n][c] = relu( mean_thw(x) + mean_t,hw(m4) )
// ---------------------------------------------------------------------------
__global__ __launch_bounds__(256) void final_reduce_kernel(const float* __restrict__ x,
    const float* __restrict__ m4, float* __restrict__ r) {
  const int nc = blockIdx.x;
  const int n = nc >> 8, c = nc & 255;
  const int tid = threadIdx.x;
  const float* xs = x + (size_t)nc * 6272;
  float s = 0.f;
  for (int i = tid; i < 6272; i += 256) s += xs[i];
  float s2 = 0.f;
  for (int t = 0; t < 7; ++t) {
    const float* ms = m4 + ((size_t)(n * 7 + t) * 256 + c) * 676;
    for (int i = tid; i < 676; i += 256) s2 += ms[i];
  }
  float v = s * (1.f / 6272.f) + s2 * (1.f / 4732.f);
#pragma unroll
  for (int off = 32; off; off >>= 1) v += __shfl_down(v, off);
  __shared__ float red[4];
  if ((tid & 63) == 0) red[tid >> 6] = v;
  __syncthreads();
  if (tid == 0) r[nc] = fmaxf(red[0] + red[1] + red[2] + red[3], 0.f);
}

__global__ __launch_bounds__(256) void linear_kernel(const float* __restrict__ r,
    const float* __restrict__ lw, const float* __restrict__ lb,
    float* __restrict__ out) {
  const int n = blockIdx.x;
  const int j = threadIdx.x;
  __shared__ float rl[256];
  rl[j] = r[n * 256 + j];
  __syncthreads();
  float acc = lb[j];
  const float* w = lw + (size_t)j * 256;
#pragma unroll 4
  for (int c = 0; c < 256; c += 4) {
    const float4 wv = *(const float4*)&w[c];
    acc += wv.x * rl[c] + wv.y * rl[c + 1] + wv.z * rl[c + 2] + wv.w * rl[c + 3];
  }
  out[n * 256 + j] = acc;
}

extern "C" void kernel_launch(void* const* d_in, const int* in_sizes, int n_in,
                              void* d_out, int out_size, void* d_ws, size_t ws_size,
                              hipStream_t stream) {
  const float* x      = (const float*)d_in[0];
  const float* corr_w = (const float*)d_in[1];
  const float* corr_b = (const float*)d_in[2];
  const float* mw1 = (const float*)d_in[3];
  const float* mb1 = (const float*)d_in[4];
  const float* mw2 = (const float*)d_in[5];
  const float* mb2 = (const float*)d_in[6];
  const float* mw3 = (const float*)d_in[7];
  const float* mb3 = (const float*)d_in[8];
  const float* mw4 = (const float*)d_in[9];
  const float* mb4 = (const float*)d_in[10];
  const float* lin_w = (const float*)d_in[11];
  const float* lin_b = (const float*)d_in[12];
  float* out = (float*)d_out;
  char* wsb = (char*)d_ws;

  // workspace map (bytes), total 34.73 MB. tm_t [0,6.4M) dead after score;
  // m4 [0,19.4M) written by conv4 (after score) -> safe alias.
  ushort* tmt = (ushort*)(wsb + 0);          //  6,422,528 B
  float*  m4  = (float*)(wsb + 0);           // 19,382,272 B
  float*  m0  = (float*)(wsb + 19382272);    //    263,424 B
  float*  rr  = (float*)(wsb + 19645696);    //      4,096 B
  ushort* m1  = (ushort*)(wsb + 19649792);   //  2,809,856 B bf16 padded
  ushort* m2  = (ushort*)(wsb + 22459648);   //  5,619,712 B
  ushort* m3  = (ushort*)(wsb + 28079360);   //  5,619,712 B
  ushort* Bp2 = (ushort*)(wsb + 33699072);   //    147,456 B
  ushort* Bp3 = (ushort*)(wsb + 33846528);   //    294,912 B
  ushort* Bp4 = (ushort*)(wsb + 34141440);   //    589,824 B

  hipMemsetAsync(m1, 0, 2809856, stream);
  hipMemsetAsync(m2, 0, 5619712, stream);
  hipMemsetAsync(m3, 0, 5619712, stream);

  pack_w_kernel<<<dim3(288), 256, 0, stream>>>(mw2, Bp2, 64, 8, 73728);
  pack_w_kernel<<<dim3(576), 256, 0, stream>>>(mw3, Bp3, 128, 8, 147456);
  pack_w_kernel<<<dim3(1152), 256, 0, stream>>>(mw4, Bp4, 128, 16, 294912);

  tm_kernel<<<dim3(4, 4, 32), 256, 0, stream>>>(x, corr_w, corr_b, tmt);
  score_kernel<<<dim3(49, 28), 256, 0, stream>>>(tmt, m0);
  conv1_kernel<<<dim3(4, 28), 256, 0, stream>>>(m0, mw1, mb1, m1);
  conv_mfma_kernel<64, false><<<dim3(6, 28, 2), 128, 0, stream>>>(
      m1, Bp2, mb2, m2, nullptr, 128);
  conv_mfma_kernel<128, false><<<dim3(6, 28, 2), 128, 0, stream>>>(
      m2, Bp3, mb3, m3, nullptr, 128);
  conv_mfma_kernel<128, true><<<dim3(6, 28, 4), 128, 0, stream>>>(
      m3, Bp4, mb4, nullptr, m4, 256);
  final_reduce_kernel<<<dim3(1024), 256, 0, stream>>>(x, m4, rr);
  linear_kernel<<<dim3(4), 256, 0, stream>>>(rr, lin_w, lin_b, out);
}

// Round 5
// 341.241 us; speedup vs baseline: 3.1821x; 1.0419x over previous
//
#include <hip/hip_runtime.h>

// Pipeline (all fixed shapes):
// x[4][256][8][28][28] fp32
//  -> xb (relu, bf16 hi/lo, ch-last)  [32nt*784][256] x2
//  -> tm_gemm (MFMA, hi/lo = ~fp32)   tmt [32nt*784][128] bf16
//  -> score (MFMA GEMM + argmax + 2x softmax) m0 [28][3][784] fp32
//  -> conv1 (fp32 direct)             m1 [28][784][64]  bf16 padded ch-last
//  -> conv2/3/4 (MFMA implicit GEMM, M=28*676 merged) m2,m3 padded; m4 fp32
//  -> final_reduce + linear           out [4][256] fp32

#define NORM_INV 0.07978845608028654f   // 1/(sqrt(2*pi)*5)

typedef __attribute__((ext_vector_type(8))) short bf16x8;
typedef __attribute__((ext_vector_type(4))) float f32x4;

__device__ inline ushort f2bf(float v) {
  union { float f; uint u; } c; c.f = v;
  const uint u = c.u + 0x7FFFu + ((c.u >> 16) & 1u);   // RNE
  return (ushort)(u >> 16);
}
__device__ inline float bf2f(ushort h) {
  union { uint u; float f; } c; c.u = ((uint)h) << 16;
  return c.f;
}

// ---------------------------------------------------------------------------
// xb: transpose x[n][c][t][hw] -> ch-last bf16 hi/lo with relu.
// grid (13 pix-tiles of 64, 4 c-tiles of 64, 32 nt), 256 thr. LDS transpose.
// ---------------------------------------------------------------------------
__global__ __launch_bounds__(256) void xb_kernel(const float* __restrict__ x,
    ushort* __restrict__ xh, ushort* __restrict__ xl) {
  const int tid = threadIdx.x;
  const int p0 = blockIdx.x * 64;
  const int c0 = blockIdx.y * 64;
  const int nt = blockIdx.z;
  const int n = nt >> 3, t = nt & 7;
  __shared__ float tile[64][65];
  const float* xp = x + (((size_t)n * 256 + c0) * 8 + t) * 784;
#pragma unroll
  for (int i = 0; i < 16; ++i) {
    const int idx = i * 256 + tid;
    const int c = idx >> 6, p = idx & 63;
    const int hw = p0 + p;
    tile[p][c] = (hw < 784) ? xp[(size_t)c * 6272 + hw] : 0.f;
  }
  __syncthreads();
#pragma unroll
  for (int i = 0; i < 8; ++i) {
    const int idx = i * 256 + tid;
    const int p = idx >> 5, c2 = (idx & 31) * 2;
    const int hw = p0 + p;
    if (hw < 784) {
      const size_t o = ((size_t)nt * 784 + hw) * 256 + c0 + c2;
      const float v0 = fmaxf(tile[p][c2], 0.f);
      const float v1 = fmaxf(tile[p][c2 + 1], 0.f);
      const ushort h0 = f2bf(v0), h1 = f2bf(v1);
      ushort2 hv, lv;
      hv.x = h0; hv.y = h1;
      lv.x = f2bf(v0 - bf2f(h0)); lv.y = f2bf(v1 - bf2f(h1));
      *(ushort2*)(xh + o) = hv;
      *(ushort2*)(xl + o) = lv;
    }
  }
}

// ---------------------------------------------------------------------------
// pack corr_w [128][256] fp32 -> MFMA B layout [8 kc][8 n16][64 l][8 j], hi/lo
// ---------------------------------------------------------------------------
__global__ __launch_bounds__(256) void pack_cw_kernel(const float* __restrict__ cw,
    ushort* __restrict__ bh, ushort* __restrict__ bl) {
  const int idx = blockIdx.x * 256 + threadIdx.x;   // 32768 total
  const int j = idx & 7, l = (idx >> 3) & 63, rest = idx >> 9;
  const int n16 = rest & 7, kc = rest >> 3;
  const int co = n16 * 16 + (l & 15);
  const int k = kc * 32 + (l >> 4) * 8 + j;
  const float v = cw[co * 256 + k];
  const ushort h = f2bf(v);
  bh[idx] = h;
  bl[idx] = f2bf(v - bf2f(h));
}

// ---------------------------------------------------------------------------
// tm GEMM: tmt[pix][co] = bf16( xb[pix][:] . cw[co][:] + cb[co] ), hi/lo MFMA.
// Wave tile 32 pix x 32 co. grid (196, 4), 256 thr = 4 waves (M-stacked).
// ---------------------------------------------------------------------------
__global__ __launch_bounds__(256) void tm_gemm_kernel(
    const ushort* __restrict__ xh, const ushort* __restrict__ xl,
    const ushort* __restrict__ bph, const ushort* __restrict__ bpl,
    const float* __restrict__ cb, ushort* __restrict__ tmt) {
  const int tid = threadIdx.x;
  const int w = tid >> 6, l = tid & 63;
  const int lr = l & 15, lq = l >> 4;
  const int mtile = blockIdx.x * 4 + w;     // 0..783
  const int ntile = blockIdx.y;             // 0..3
  const size_t r0 = (size_t)(mtile * 32 + lr) * 256 + lq * 8;
  const size_t r1 = r0 + 16 * 256;
  f32x4 acc[2][2];
#pragma unroll
  for (int mf = 0; mf < 2; ++mf)
#pragma unroll
    for (int nf = 0; nf < 2; ++nf) { f32x4 z = {0.f,0.f,0.f,0.f}; acc[mf][nf] = z; }
#pragma unroll
  for (int kc = 0; kc < 8; ++kc) {
    const bf16x8 ah0 = *(const bf16x8*)(xh + r0 + kc * 32);
    const bf16x8 ah1 = *(const bf16x8*)(xh + r1 + kc * 32);
    const bf16x8 al0 = *(const bf16x8*)(xl + r0 + kc * 32);
    const bf16x8 al1 = *(const bf16x8*)(xl + r1 + kc * 32);
    const size_t bo = ((size_t)(kc * 8 + ntile * 2) * 64 + l) * 8;
    const bf16x8 bh0 = *(const bf16x8*)(bph + bo);
    const bf16x8 bh1 = *(const bf16x8*)(bph + bo + 512);
    const bf16x8 bl0 = *(const bf16x8*)(bpl + bo);
    const bf16x8 bl1 = *(const bf16x8*)(bpl + bo + 512);
    acc[0][0] = __builtin_amdgcn_mfma_f32_16x16x32_bf16(ah0, bh0, acc[0][0], 0,0,0);
    acc[0][1] = __builtin_amdgcn_mfma_f32_16x16x32_bf16(ah0, bh1, acc[0][1], 0,0,0);
    acc[1][0] = __builtin_amdgcn_mfma_f32_16x16x32_bf16(ah1, bh0, acc[1][0], 0,0,0);
    acc[1][1] = __builtin_amdgcn_mfma_f32_16x16x32_bf16(ah1, bh1, acc[1][1], 0,0,0);
    acc[0][0] = __builtin_amdgcn_mfma_f32_16x16x32_bf16(al0, bh0, acc[0][0], 0,0,0);
    acc[0][1] = __builtin_amdgcn_mfma_f32_16x16x32_bf16(al0, bh1, acc[0][1], 0,0,0);
    acc[1][0] = __builtin_amdgcn_mfma_f32_16x16x32_bf16(al1, bh0, acc[1][0], 0,0,0);
    acc[1][1] = __builtin_amdgcn_mfma_f32_16x16x32_bf16(al1, bh1, acc[1][1], 0,0,0);
    acc[0][0] = __builtin_amdgcn_mfma_f32_16x16x32_bf16(ah0, bl0, acc[0][0], 0,0,0);
    acc[0][1] = __builtin_amdgcn_mfma_f32_16x16x32_bf16(ah0, bl1, acc[0][1], 0,0,0);
    acc[1][0] = __builtin_amdgcn_mfma_f32_16x16x32_bf16(ah1, bl0, acc[1][0], 0,0,0);
    acc[1][1] = __builtin_amdgcn_mfma_f32_16x16x32_bf16(ah1, bl1, acc[1][1], 0,0,0);
  }
#pragma unroll
  for (int nf = 0; nf < 2; ++nf) {
    const int co = ntile * 32 + nf * 16 + lr;
    const float bv = cb[co];
#pragma unroll
    for (int mf = 0; mf < 2; ++mf)
#pragma unroll
      for (int r = 0; r < 4; ++r) {
        const int pix = mtile * 32 + mf * 16 + lq * 4 + r;
        tmt[(size_t)pix * 128 + co] = f2bf(acc[mf][nf][r] + bv);
      }
  }
}

// ---------------------------------------------------------------------------
// score: MFMA GEMM (16 uv x 784 ab, K=128) + argmax + double softmax.
// 512 thr = 8 waves (ab-split GEMM); softmax 32 lanes per uv row.
// grid (49, 28).
// ---------------------------------------------------------------------------
__global__ __launch_bounds__(512) void score_kernel(const ushort* __restrict__ tmt,
    float* __restrict__ m0) {
  const int tid = threadIdx.x;
  const int nt = blockIdx.y;
  const int n = nt / 7, t = nt % 7;
  const int uv0 = blockIdx.x * 16;
  const ushort* bfp = tmt + (size_t)(n * 8 + t) * 784 * 128;      // frame t
  const ushort* bhp = tmt + (size_t)(n * 8 + t + 1) * 784 * 128;  // frame t+1
  __shared__ float sc[16 * 785];
  __shared__ float gt[16 * 64];
  const int w = tid >> 6;
  const int l = tid & 63;
  const int lr = l & 15, lq = l >> 4;
  bf16x8 af[4];
#pragma unroll
  for (int kc = 0; kc < 4; ++kc)
    af[kc] = *(const bf16x8*)(bfp + (uv0 + lr) * 128 + kc * 32 + lq * 8);
  f32x4 acc[7];
#pragma unroll
  for (int i = 0; i < 7; ++i) { f32x4 z = {0.f,0.f,0.f,0.f}; acc[i] = z; }
#pragma unroll
  for (int i = 0; i < 7; ++i) {
    const int nf = i * 8 + w;
    if (nf < 49) {
      const ushort* bp = bhp + (nf * 16 + lr) * 128 + lq * 8;
      const bf16x8 b0 = *(const bf16x8*)(bp);
      const bf16x8 b1 = *(const bf16x8*)(bp + 32);
      const bf16x8 b2 = *(const bf16x8*)(bp + 64);
      const bf16x8 b3 = *(const bf16x8*)(bp + 96);
      acc[i] = __builtin_amdgcn_mfma_f32_16x16x32_bf16(af[0], b0, acc[i], 0,0,0);
      acc[i] = __builtin_amdgcn_mfma_f32_16x16x32_bf16(af[1], b1, acc[i], 0,0,0);
      acc[i] = __builtin_amdgcn_mfma_f32_16x16x32_bf16(af[2], b2, acc[i], 0,0,0);
      acc[i] = __builtin_amdgcn_mfma_f32_16x16x32_bf16(af[3], b3, acc[i], 0,0,0);
    }
  }
#pragma unroll
  for (int i = 0; i < 7; ++i) {
    const int nf = i * 8 + w;
    if (nf < 49) {
#pragma unroll
      for (int r = 0; r < 4; ++r)
        sc[(lq * 4 + r) * 785 + nf * 16 + lr] = acc[i][r];
    }
  }
  __syncthreads();
  // ---- softmax: 32 lanes per uv row
  const int row = tid >> 5, l32 = tid & 31;
  const float* rowp = &sc[row * 785];
  float bv = -1e30f; int bi = 0;
#pragma unroll 5
  for (int i = 0; i < 25; ++i) {
    const int a2 = i * 32 + l32;
    if (a2 < 784) {
      const float v = rowp[a2];
      if (v > bv) { bv = v; bi = a2; }
    }
  }
#pragma unroll
  for (int off = 16; off; off >>= 1) {
    const float ov = __shfl_xor(bv, off, 32);
    const int oi = __shfl_xor(bi, off, 32);
    if (ov > bv || (ov == bv && oi < bi)) { bv = ov; bi = oi; }
  }
  const int ast = bi / 28;
  const int bst = bi - ast * 28;
  float* g = &gt[row * 64];
  if (l32 < 28) {
    g[l32]      = __expf((float)(l32 - ast) * 0.04f) * NORM_INV;
    g[32 + l32] = __expf((float)(l32 - bst) * 0.04f) * NORM_INV;
  }
  float mx = -1e30f, my = -1e30f;
#pragma unroll 5
  for (int i = 0; i < 25; ++i) {
    const int a2 = i * 32 + l32;
    if (a2 < 784) {
      const float v = rowp[a2];
      const int a = a2 / 28; const int bb = a2 - a * 28;
      mx = fmaxf(mx, g[a] * v); my = fmaxf(my, g[32 + bb] * v);
    }
  }
#pragma unroll
  for (int off = 16; off; off >>= 1) {
    mx = fmaxf(mx, __shfl_xor(mx, off, 32));
    my = fmaxf(my, __shfl_xor(my, off, 32));
  }
  float sx = 0.f, sxw = 0.f, sy = 0.f, syw = 0.f;
#pragma unroll 5
  for (int i = 0; i < 25; ++i) {
    const int a2 = i * 32 + l32;
    if (a2 < 784) {
      const float v = rowp[a2];
      const int a = a2 / 28; const int bb = a2 - a * 28;
      const float ex = __expf((g[a] * v - mx) * 100.f);
      const float ey = __expf((g[32 + bb] * v - my) * 100.f);
      sx += ex; sxw += (float)a * ex;
      sy += ey; syw += (float)bb * ey;
    }
  }
#pragma unroll
  for (int off = 16; off; off >>= 1) {
    sx += __shfl_xor(sx, off, 32); sxw += __shfl_xor(sxw, off, 32);
    sy += __shfl_xor(sy, off, 32); syw += __shfl_xor(syw, off, 32);
  }
  if (l32 == 0) {
    const int uv = uv0 + row;
    float* op = m0 + (size_t)nt * 3 * 784 + uv;
    op[0]    = fmaxf(sxw / sx, 0.f);
    op[784]  = fmaxf(syw / sy, 0.f);
    op[1568] = fmaxf(bv, 0.f);
  }
}

// ---------------------------------------------------------------------------
// conv1: 3 -> 64, K=5, fp32 direct; writes bf16 padded ch-last m1.
// grid (4 co-tiles, 3 pix-groups, 28 b), 256 thr.
// ---------------------------------------------------------------------------
__global__ __launch_bounds__(256) void conv1_kernel(const float* __restrict__ m0,
    const float* __restrict__ w, const float* __restrict__ bias,
    ushort* __restrict__ out) {
  const int b = blockIdx.z;
  const int pg = blockIdx.y;
  const int co0 = blockIdx.x * 16;
  const int tid = threadIdx.x;
  __shared__ float il[3 * 784];
  __shared__ float wl[75 * 16];
  const float* ip = m0 + (size_t)b * 2352;
  for (int i = tid; i < 2352; i += 256) il[i] = ip[i];
  for (int i = tid; i < 1200; i += 256) {
    const int c = i & 15, rest = i >> 4;
    wl[i] = w[(size_t)(co0 + c) * 75 + rest];
  }
  __syncthreads();
  const int pix = pg * 256 + tid;
  if (pix >= 676) return;
  const int py = pix / 26, px = pix - py * 26;
  float acc[16];
#pragma unroll
  for (int c = 0; c < 16; ++c) acc[c] = 0.f;
  for (int ci = 0; ci < 3; ++ci) {
#pragma unroll
    for (int dy = 0; dy < 5; ++dy) {
      const int iy = py + dy - 1;
      if ((unsigned)iy >= 28u) continue;
#pragma unroll
      for (int dx = 0; dx < 5; ++dx) {
        const int ix = px + dx - 1;
        if ((unsigned)ix >= 28u) continue;
        const float v = il[ci * 784 + iy * 28 + ix];
        const float* wp = &wl[(ci * 25 + dy * 5 + dx) * 16];
#pragma unroll
        for (int c4 = 0; c4 < 16; c4 += 4) {
          const float4 wv = *(const float4*)&wp[c4];
          acc[c4 + 0] += wv.x * v; acc[c4 + 1] += wv.y * v;
          acc[c4 + 2] += wv.z * v; acc[c4 + 3] += wv.w * v;
        }
      }
    }
  }
  const int ipo = (py + 1) * 28 + px + 1;
  ushort* op = out + ((size_t)b * 784 + ipo) * 64 + co0;
#pragma unroll
  for (int c = 0; c < 16; ++c)
    op[c] = f2bf(fmaxf(acc[c] + bias[co0 + c], 0.f));
}

// ---------------------------------------------------------------------------
// conv weight pack: mw [COUT][CIN][3][3] fp32 -> [kc][n16][64][8] bf16.
// ---------------------------------------------------------------------------
__global__ __launch_bounds__(256) void pack_w_kernel(const float* __restrict__ w,
    ushort* __restrict__ Bp, int CIN, int N16, int total) {
  const int idx = blockIdx.x * 256 + threadIdx.x;
  if (idx >= total) return;
  const int j = idx & 7;
  const int l = (idx >> 3) & 63;
  const int rest = idx >> 9;
  const int n16 = rest % N16;
  const int kc = rest / N16;
  const int co = n16 * 16 + (l & 15);
  const int kk = kc * 32 + (l >> 4) * 8 + j;
  const int tap = kk / CIN;
  const int ci = kk - tap * CIN;
  Bp[idx] = f2bf(w[((size_t)co * CIN + ci) * 9 + tap]);
}

// ---------------------------------------------------------------------------
// MFMA implicit-GEMM conv, batch merged into M (M = 28*676 = 18928).
// Wave tile 32 pix x 32 cout; block = 4 waves (M-stacked). grid (148, cout/32).
// ---------------------------------------------------------------------------
template<int CIN, bool FINAL>
__global__ __launch_bounds__(256) void conv_mfma2_kernel(
    const ushort* __restrict__ in, const ushort* __restrict__ Bp,
    const float* __restrict__ bias, ushort* __restrict__ outp,
    float* __restrict__ outf, int COUTC) {
  constexpr int KC = CIN * 9 / 32;          // 18 or 36 (even)
  constexpr int CPG = CIN / 32;
  const int N16 = COUTC >> 4;
  const int tid = threadIdx.x;
  const int w = tid >> 6, l = tid & 63;
  const int lr = l & 15, lq = l >> 4;
  const int mtile = blockIdx.x * 4 + w;     // 0..591
  const int ntile = blockIdx.y;
  const ushort* aP[2];
#pragma unroll
  for (int mf = 0; mf < 2; ++mf) {
    int P = mtile * 32 + mf * 16 + lr;
    if (P > 18927) P = 18927;
    const int b = P / 676;
    const int pp = P - b * 676;
    const int ipb = pp + 2 * (pp / 26);
    aP[mf] = in + ((size_t)b * 784 + ipb) * CIN;
  }
  f32x4 acc[2][2];
#pragma unroll
  for (int mf = 0; mf < 2; ++mf)
#pragma unroll
    for (int nf = 0; nf < 2; ++nf) { f32x4 z = {0.f,0.f,0.f,0.f}; acc[mf][nf] = z; }

  auto loadA = [&](int kc, bf16x8* a) {
    const int tap = kc / CPG;
    const int ci0 = (kc - tap * CPG) * 32 + lq * 8;
    const int off = (tap / 3) * 28 + (tap - (tap / 3) * 3);
    a[0] = *(const bf16x8*)(aP[0] + (size_t)off * CIN + ci0);
    a[1] = *(const bf16x8*)(aP[1] + (size_t)off * CIN + ci0);
  };
  auto loadB = [&](int kc, bf16x8* bb) {
    const ushort* bp = Bp + (((size_t)kc * N16 + ntile * 2) * 64 + l) * 8;
    bb[0] = *(const bf16x8*)bp;
    bb[1] = *(const bf16x8*)(bp + 512);
  };
  auto domfma = [&](bf16x8* a, bf16x8* bb) {
    acc[0][0] = __builtin_amdgcn_mfma_f32_16x16x32_bf16(a[0], bb[0], acc[0][0], 0,0,0);
    acc[0][1] = __builtin_amdgcn_mfma_f32_16x16x32_bf16(a[0], bb[1], acc[0][1], 0,0,0);
    acc[1][0] = __builtin_amdgcn_mfma_f32_16x16x32_bf16(a[1], bb[0], acc[1][0], 0,0,0);
    acc[1][1] = __builtin_amdgcn_mfma_f32_16x16x32_bf16(a[1], bb[1], acc[1][1], 0,0,0);
  };

  bf16x8 aA[2], bA[2], aB[2], bB[2];
  loadA(0, aA); loadB(0, bA);
  for (int kc = 0; kc < KC; kc += 2) {
    loadA(kc + 1, aB); loadB(kc + 1, bB);
    domfma(aA, bA);
    if (kc + 2 < KC) { loadA(kc + 2, aA); loadB(kc + 2, bA); }
    domfma(aB, bB);
  }
#pragma unroll
  for (int nf = 0; nf < 2; ++nf) {
    const int co = ntile * 32 + nf * 16 + lr;
    const float bvv = bias[co];
#pragma unroll
    for (int mf = 0; mf < 2; ++mf) {
#pragma unroll
      for (int r = 0; r < 4; ++r) {
        const int P = mtile * 32 + mf * 16 + lq * 4 + r;
        if (P < 18928) {
          const int b = P / 676;
          const int pp = P - b * 676;
          const float v = acc[mf][nf][r] + bvv;
          if constexpr (FINAL) {
            outf[((size_t)b * COUTC + co) * 676 + pp] = v;
          } else {
            const int ipo = pp + 2 * (pp / 26) + 29;
            outp[((size_t)b * 784 + ipo) * COUTC + co] = f2bf(fmaxf(v, 0.f));
          }
        }
      }
    }
  }
}

// ---------------------------------------------------------------------------
// D1: r[n][c] = relu( mean_thw(x) + mean_t,hw(m4) ); one block per (n,c)
// ---------------------------------------------------------------------------
__global__ __launch_bounds__(256) void final_reduce_kernel(const float* __restrict__ x,
    const float* __restrict__ m4, float* __restrict__ r) {
  const int nc = blockIdx.x;
  const int n = nc >> 8, c = nc & 255;
  const int tid = threadIdx.x;
  const float* xs = x + (size_t)nc * 6272;
  float s = 0.f;
  for (int i = tid; i < 6272; i += 256) s += xs[i];
  float s2 = 0.f;
  for (int t = 0; t < 7; ++t) {
    const float* ms = m4 + ((size_t)(n * 7 + t) * 256 + c) * 676;
    for (int i = tid; i < 676; i += 256) s2 += ms[i];
  }
  float v = s * (1.f / 6272.f) + s2 * (1.f / 4732.f);
#pragma unroll
  for (int off = 32; off; off >>= 1) v += __shfl_down(v, off);
  __shared__ float red[4];
  if ((tid & 63) == 0) red[tid >> 6] = v;
  __syncthreads();
  if (tid == 0) r[nc] = fmaxf(red[0] + red[1] + red[2] + red[3], 0.f);
}

__global__ __launch_bounds__(256) void linear_kernel(const float* __restrict__ r,
    const float* __restrict__ lw, const float* __restrict__ lb,
    float* __restrict__ out) {
  const int n = blockIdx.x;
  const int j = threadIdx.x;
  __shared__ float rl[256];
  rl[j] = r[n * 256 + j];
  __syncthreads();
  float acc = lb[j];
  const float* w = lw + (size_t)j * 256;
#pragma unroll 4
  for (int c = 0; c < 256; c += 4) {
    const float4 wv = *(const float4*)&w[c];
    acc += wv.x * rl[c] + wv.y * rl[c + 1] + wv.z * rl[c + 2] + wv.w * rl[c + 3];
  }
  out[n * 256 + j] = acc;
}

extern "C" void kernel_launch(void* const* d_in, const int* in_sizes, int n_in,
                              void* d_out, int out_size, void* d_ws, size_t ws_size,
                              hipStream_t stream) {
  const float* x      = (const float*)d_in[0];
  const float* corr_w = (const float*)d_in[1];
  const float* corr_b = (const float*)d_in[2];
  const float* mw1 = (const float*)d_in[3];
  const float* mb1 = (const float*)d_in[4];
  const float* mw2 = (const float*)d_in[5];
  const float* mb2 = (const float*)d_in[6];
  const float* mw3 = (const float*)d_in[7];
  const float* mb3 = (const float*)d_in[8];
  const float* mw4 = (const float*)d_in[9];
  const float* mb4 = (const float*)d_in[10];
  const float* lin_w = (const float*)d_in[11];
  const float* lin_b = (const float*)d_in[12];
  float* out = (float*)d_out;
  char* wsb = (char*)d_ws;

  // workspace map (bytes), total 34.86 MB (round-1 proved ws >= 38.77 MB).
  // xh/xl/tmt dead after score; m1/m2/m3/m4 alias them (written after score).
  ushort* xh  = (ushort*)(wsb + 0);          // 12,845,056
  ushort* xl  = (ushort*)(wsb + 12845056);   // 12,845,056 -> 25,690,112
  ushort* tmt = (ushort*)(wsb + 25690112);   //  6,422,528 -> 32,112,640
  float*  m4  = (float*)(wsb + 0);           // 19,382,272 (conv4, after score)
  ushort* m1  = (ushort*)(wsb + 19382272);   //  2,809,856 -> 22,192,128
  ushort* m2  = (ushort*)(wsb + 22192128);   //  5,619,712 -> 27,811,840
  ushort* m3  = (ushort*)(wsb + 27811840);   //  5,619,712 -> 33,431,552
  float*  m0  = (float*)(wsb + 33431552);    //    263,424 -> 33,694,976
  float*  rr  = (float*)(wsb + 33694976);    //      4,096 -> 33,699,072
  ushort* Bp2 = (ushort*)(wsb + 33699072);   //    147,456 -> 33,846,528
  ushort* Bp3 = (ushort*)(wsb + 33846528);   //    294,912 -> 34,141,440
  ushort* Bp4 = (ushort*)(wsb + 34141440);   //    589,824 -> 34,731,264
  ushort* Bph = (ushort*)(wsb + 34731264);   //     65,536 -> 34,796,800
  ushort* Bpl = (ushort*)(wsb + 34796800);   //     65,536 -> 34,862,336

  // weight packs (no deps)
  pack_cw_kernel<<<dim3(128), 256, 0, stream>>>(corr_w, Bph, Bpl);
  pack_w_kernel<<<dim3(288), 256, 0, stream>>>(mw2, Bp2, 64, 8, 73728);
  pack_w_kernel<<<dim3(576), 256, 0, stream>>>(mw3, Bp3, 128, 8, 147456);
  pack_w_kernel<<<dim3(1152), 256, 0, stream>>>(mw4, Bp4, 128, 16, 294912);

  // tm path
  xb_kernel<<<dim3(13, 4, 32), 256, 0, stream>>>(x, xh, xl);
  tm_gemm_kernel<<<dim3(196, 4), 256, 0, stream>>>(xh, xl, Bph, Bpl, corr_b, tmt);
  score_kernel<<<dim3(49, 28), 512, 0, stream>>>(tmt, m0);

  // zero padded conv activation borders (regions alias dead xb/tmt -> after score)
  hipMemsetAsync(m1, 0, 2809856, stream);
  hipMemsetAsync(m2, 0, 5619712, stream);
  hipMemsetAsync(m3, 0, 5619712, stream);

  conv1_kernel<<<dim3(4, 3, 28), 256, 0, stream>>>(m0, mw1, mb1, m1);
  conv_mfma2_kernel<64, false><<<dim3(148, 4), 256, 0, stream>>>(
      m1, Bp2, mb2, m2, nullptr, 128);
  conv_mfma2_kernel<128, false><<<dim3(148, 4), 256, 0, stream>>>(
      m2, Bp3, mb3, m3, nullptr, 128);
  conv_mfma2_kernel<128, true><<<dim3(148, 8), 256, 0, stream>>>(
      m3, Bp4, mb4, nullptr, m4, 256);
  final_reduce_kernel<<<dim3(1024), 256, 0, stream>>>(x, m4, rr);
  linear_kernel<<<dim3(4), 256, 0, stream>>>(rr, lin_w, lin_b, out);
}

// Round 6
// 288.897 us; speedup vs baseline: 3.7587x; 1.1812x over previous
//
#include <hip/hip_runtime.h>

// Pipeline (fixed shapes):
// x[4][256][8][28][28] fp32
//  -> xb (relu, bf16 hi/lo, ch-last; fused x-mean atomicAdd into y)
//  -> tm_gemm (MFMA hi/lo ~fp32)   tmt [32nt*784][128] bf16
//  -> score (MFMA GEMM + argmax + 2 softmax) m0 [28][3][784] fp32
//  -> conv1 fp32 direct            m1 [28][784][64]  bf16 padded ch-last
//  -> conv_lds 2/3/4 (MFMA implicit GEMM, LDS double-buffered via
//     global_load_lds; M = 28*676 merged)  m2,m3 padded bf16; m4 fp32
//  -> final_reduce (y + m4) + linear -> out [4][256] fp32

#define NORM_INV 0.07978845608028654f   // 1/(sqrt(2*pi)*5)

typedef __attribute__((ext_vector_type(8))) short bf16x8;
typedef __attribute__((ext_vector_type(4))) float f32x4;

__device__ inline ushort f2bf(float v) {
  union { float f; uint u; } c; c.f = v;
  const uint u = c.u + 0x7FFFu + ((c.u >> 16) & 1u);   // RNE
  return (ushort)(u >> 16);
}
__device__ inline float bf2f(ushort h) {
  union { uint u; float f; } c; c.u = ((uint)h) << 16;
  return c.f;
}

// async global->LDS, 16B per lane. dest must be wave-uniform base (+lane*16 HW).
__device__ __forceinline__ void glds16(const void* g, void* l) {
  __builtin_amdgcn_global_load_lds(
      (const __attribute__((address_space(1))) void*)g,
      (__attribute__((address_space(3))) void*)l, 16, 0, 0);
}

// ---------------------------------------------------------------------------
// pack_all: corr_w hi/lo + conv2/3/4 weight packs + zero y. One dispatch.
// ---------------------------------------------------------------------------
__device__ __forceinline__ void pack_w_one(const float* __restrict__ w,
    ushort* __restrict__ Bp, int CIN, int N16, int idx) {
  const int j = idx & 7;
  const int l = (idx >> 3) & 63;
  const int rest = idx >> 9;
  const int n16 = rest % N16;
  const int kc = rest / N16;
  const int co = n16 * 16 + (l & 15);
  const int kk = kc * 32 + (l >> 4) * 8 + j;
  const int tap = kk / CIN;
  const int ci = kk - tap * CIN;
  Bp[idx] = f2bf(w[((size_t)co * CIN + ci) * 9 + tap]);
}

__global__ __launch_bounds__(256) void pack_all_kernel(
    const float* __restrict__ cw, const float* __restrict__ mw2,
    const float* __restrict__ mw3, const float* __restrict__ mw4,
    ushort* __restrict__ bph, ushort* __restrict__ bpl,
    ushort* __restrict__ bp2, ushort* __restrict__ bp3,
    ushort* __restrict__ bp4, float* __restrict__ y) {
  int idx = blockIdx.x * 256 + threadIdx.x;
  if (idx < 32768) {            // corr_w hi/lo: [8 kc][8 n16][64][8]
    const int j = idx & 7, l = (idx >> 3) & 63, rest = idx >> 9;
    const int n16 = rest & 7, kc = rest >> 3;
    const int co = n16 * 16 + (l & 15);
    const int k = kc * 32 + (l >> 4) * 8 + j;
    const float v = cw[co * 256 + k];
    const ushort h = f2bf(v);
    bph[idx] = h;
    bpl[idx] = f2bf(v - bf2f(h));
    return;
  }
  idx -= 32768;
  if (idx < 73728)  { pack_w_one(mw2, bp2, 64, 8, idx);  return; }
  idx -= 73728;
  if (idx < 147456) { pack_w_one(mw3, bp3, 128, 8, idx); return; }
  idx -= 147456;
  if (idx < 294912) { pack_w_one(mw4, bp4, 128, 16, idx); return; }
  idx -= 294912;
  if (idx < 1024) y[idx] = 0.f;
}

// ---------------------------------------------------------------------------
// xb: x[n][c][t][hw] -> ch-last bf16 hi/lo with relu; fused raw-x mean -> y.
// grid (13 pix-tiles of 64, 4 c-tiles of 64, 32 nt), 256 thr.
// ---------------------------------------------------------------------------
__global__ __launch_bounds__(256) void xb_kernel(const float* __restrict__ x,
    ushort* __restrict__ xh, ushort* __restrict__ xl, float* __restrict__ y) {
  const int tid = threadIdx.x;
  const int p0 = blockIdx.x * 64;
  const int c0 = blockIdx.y * 64;
  const int nt = blockIdx.z;
  const int n = nt >> 3, t = nt & 7;
  __shared__ float tile[64][65];
  const float* xp = x + (((size_t)n * 256 + c0) * 8 + t) * 784;
#pragma unroll
  for (int i = 0; i < 4; ++i) {            // float4 loads: [64 c][16 q]
    const int idx = i * 256 + tid;
    const int c = idx >> 4, q = idx & 15;
    const int hw = p0 + q * 4;
    const float* sp = xp + (size_t)c * 6272 + hw;
    if (hw + 3 < 784) {
      const float4 v = *(const float4*)sp;
      tile[q * 4 + 0][c] = v.x; tile[q * 4 + 1][c] = v.y;
      tile[q * 4 + 2][c] = v.z; tile[q * 4 + 3][c] = v.w;
    } else {
#pragma unroll
      for (int e = 0; e < 4; ++e)
        tile[q * 4 + e][c] = (hw + e < 784) ? sp[e] : 0.f;
    }
  }
  __syncthreads();
#pragma unroll
  for (int i = 0; i < 8; ++i) {
    const int idx = i * 256 + tid;
    const int p = idx >> 5, c2 = (idx & 31) * 2;
    const int hw = p0 + p;
    if (hw < 784) {
      const size_t o = ((size_t)nt * 784 + hw) * 256 + c0 + c2;
      const float v0 = fmaxf(tile[p][c2], 0.f);
      const float v1 = fmaxf(tile[p][c2 + 1], 0.f);
      const ushort h0 = f2bf(v0), h1 = f2bf(v1);
      ushort2 hv, lv;
      hv.x = h0; hv.y = h1;
      lv.x = f2bf(v0 - bf2f(h0)); lv.y = f2bf(v1 - bf2f(h1));
      *(ushort2*)(xh + o) = hv;
      *(ushort2*)(xl + o) = lv;
    }
  }
  // fused raw-x partial mean (zeros in tile for hw>=784 are harmless)
  if (tid < 64) {
    float s = 0.f;
#pragma unroll 8
    for (int p = 0; p < 64; ++p) s += tile[p][tid];
    atomicAdd(y + n * 256 + c0 + tid, s);
  }
}

// ---------------------------------------------------------------------------
// tm GEMM: tmt[pix][co] = bf16( xb[pix][:] . cw[co][:] + cb[co] ), hi/lo MFMA.
// Wave tile 32 pix x 32 co. grid (196, 4), 256 thr = 4 waves (M-stacked).
// ---------------------------------------------------------------------------
__global__ __launch_bounds__(256) void tm_gemm_kernel(
    const ushort* __restrict__ xh, const ushort* __restrict__ xl,
    const ushort* __restrict__ bph, const ushort* __restrict__ bpl,
    const float* __restrict__ cb, ushort* __restrict__ tmt) {
  const int tid = threadIdx.x;
  const int w = tid >> 6, l = tid & 63;
  const int lr = l & 15, lq = l >> 4;
  const int mtile = blockIdx.x * 4 + w;
  const int ntile = blockIdx.y;
  const size_t r0 = (size_t)(mtile * 32 + lr) * 256 + lq * 8;
  const size_t r1 = r0 + 16 * 256;
  f32x4 acc[2][2];
#pragma unroll
  for (int mf = 0; mf < 2; ++mf)
#pragma unroll
    for (int nf = 0; nf < 2; ++nf) { f32x4 z = {0.f,0.f,0.f,0.f}; acc[mf][nf] = z; }
#pragma unroll
  for (int kc = 0; kc < 8; ++kc) {
    const bf16x8 ah0 = *(const bf16x8*)(xh + r0 + kc * 32);
    const bf16x8 ah1 = *(const bf16x8*)(xh + r1 + kc * 32);
    const bf16x8 al0 = *(const bf16x8*)(xl + r0 + kc * 32);
    const bf16x8 al1 = *(const bf16x8*)(xl + r1 + kc * 32);
    const size_t bo = ((size_t)(kc * 8 + ntile * 2) * 64 + l) * 8;
    const bf16x8 bh0 = *(const bf16x8*)(bph + bo);
    const bf16x8 bh1 = *(const bf16x8*)(bph + bo + 512);
    const bf16x8 bl0 = *(const bf16x8*)(bpl + bo);
    const bf16x8 bl1 = *(const bf16x8*)(bpl + bo + 512);
    acc[0][0] = __builtin_amdgcn_mfma_f32_16x16x32_bf16(ah0, bh0, acc[0][0], 0,0,0);
    acc[0][1] = __builtin_amdgcn_mfma_f32_16x16x32_bf16(ah0, bh1, acc[0][1], 0,0,0);
    acc[1][0] = __builtin_amdgcn_mfma_f32_16x16x32_bf16(ah1, bh0, acc[1][0], 0,0,0);
    acc[1][1] = __builtin_amdgcn_mfma_f32_16x16x32_bf16(ah1, bh1, acc[1][1], 0,0,0);
    acc[0][0] = __builtin_amdgcn_mfma_f32_16x16x32_bf16(al0, bh0, acc[0][0], 0,0,0);
    acc[0][1] = __builtin_amdgcn_mfma_f32_16x16x32_bf16(al0, bh1, acc[0][1], 0,0,0);
    acc[1][0] = __builtin_amdgcn_mfma_f32_16x16x32_bf16(al1, bh0, acc[1][0], 0,0,0);
    acc[1][1] = __builtin_amdgcn_mfma_f32_16x16x32_bf16(al1, bh1, acc[1][1], 0,0,0);
    acc[0][0] = __builtin_amdgcn_mfma_f32_16x16x32_bf16(ah0, bl0, acc[0][0], 0,0,0);
    acc[0][1] = __builtin_amdgcn_mfma_f32_16x16x32_bf16(ah0, bl1, acc[0][1], 0,0,0);
    acc[1][0] = __builtin_amdgcn_mfma_f32_16x16x32_bf16(ah1, bl0, acc[1][0], 0,0,0);
    acc[1][1] = __builtin_amdgcn_mfma_f32_16x16x32_bf16(ah1, bl1, acc[1][1], 0,0,0);
  }
#pragma unroll
  for (int nf = 0; nf < 2; ++nf) {
    const int co = ntile * 32 + nf * 16 + lr;
    const float bv = cb[co];
#pragma unroll
    for (int mf = 0; mf < 2; ++mf)
#pragma unroll
      for (int r = 0; r < 4; ++r) {
        const int pix = mtile * 32 + mf * 16 + lq * 4 + r;
        tmt[(size_t)pix * 128 + co] = f2bf(acc[mf][nf][r] + bv);
      }
  }
}

// ---------------------------------------------------------------------------
// score: MFMA GEMM (16 uv x 784 ab, K=128) + argmax + double softmax.
// 512 thr = 8 waves; softmax 32 lanes per uv row. grid (49, 28).
// ---------------------------------------------------------------------------
__global__ __launch_bounds__(512) void score_kernel(const ushort* __restrict__ tmt,
    float* __restrict__ m0) {
  const int tid = threadIdx.x;
  const int nt = blockIdx.y;
  const int n = nt / 7, t = nt % 7;
  const int uv0 = blockIdx.x * 16;
  const ushort* bfp = tmt + (size_t)(n * 8 + t) * 784 * 128;
  const ushort* bhp = tmt + (size_t)(n * 8 + t + 1) * 784 * 128;
  __shared__ float sc[16 * 785];
  __shared__ float gt[16 * 64];
  const int w = tid >> 6;
  const int l = tid & 63;
  const int lr = l & 15, lq = l >> 4;
  bf16x8 af[4];
#pragma unroll
  for (int kc = 0; kc < 4; ++kc)
    af[kc] = *(const bf16x8*)(bfp + (uv0 + lr) * 128 + kc * 32 + lq * 8);
  f32x4 acc[7];
#pragma unroll
  for (int i = 0; i < 7; ++i) { f32x4 z = {0.f,0.f,0.f,0.f}; acc[i] = z; }
#pragma unroll
  for (int i = 0; i < 7; ++i) {
    const int nf = i * 8 + w;
    if (nf < 49) {
      const ushort* bp = bhp + (nf * 16 + lr) * 128 + lq * 8;
      const bf16x8 b0 = *(const bf16x8*)(bp);
      const bf16x8 b1 = *(const bf16x8*)(bp + 32);
      const bf16x8 b2 = *(const bf16x8*)(bp + 64);
      const bf16x8 b3 = *(const bf16x8*)(bp + 96);
      acc[i] = __builtin_amdgcn_mfma_f32_16x16x32_bf16(af[0], b0, acc[i], 0,0,0);
      acc[i] = __builtin_amdgcn_mfma_f32_16x16x32_bf16(af[1], b1, acc[i], 0,0,0);
      acc[i] = __builtin_amdgcn_mfma_f32_16x16x32_bf16(af[2], b2, acc[i], 0,0,0);
      acc[i] = __builtin_amdgcn_mfma_f32_16x16x32_bf16(af[3], b3, acc[i], 0,0,0);
    }
  }
#pragma unroll
  for (int i = 0; i < 7; ++i) {
    const int nf = i * 8 + w;
    if (nf < 49) {
#pragma unroll
      for (int r = 0; r < 4; ++r)
        sc[(lq * 4 + r) * 785 + nf * 16 + lr] = acc[i][r];
    }
  }
  __syncthreads();
  const int row = tid >> 5, l32 = tid & 31;
  const float* rowp = &sc[row * 785];
  float bv = -1e30f; int bi = 0;
#pragma unroll 5
  for (int i = 0; i < 25; ++i) {
    const int a2 = i * 32 + l32;
    if (a2 < 784) {
      const float v = rowp[a2];
      if (v > bv) { bv = v; bi = a2; }
    }
  }
#pragma unroll
  for (int off = 16; off; off >>= 1) {
    const float ov = __shfl_xor(bv, off, 32);
    const int oi = __shfl_xor(bi, off, 32);
    if (ov > bv || (ov == bv && oi < bi)) { bv = ov; bi = oi; }
  }
  const int ast = bi / 28;
  const int bst = bi - ast * 28;
  float* g = &gt[row * 64];
  if (l32 < 28) {
    g[l32]      = __expf((float)(l32 - ast) * 0.04f) * NORM_INV;
    g[32 + l32] = __expf((float)(l32 - bst) * 0.04f) * NORM_INV;
  }
  float mx = -1e30f, my = -1e30f;
#pragma unroll 5
  for (int i = 0; i < 25; ++i) {
    const int a2 = i * 32 + l32;
    if (a2 < 784) {
      const float v = rowp[a2];
      const int a = a2 / 28; const int bb = a2 - a * 28;
      mx = fmaxf(mx, g[a] * v); my = fmaxf(my, g[32 + bb] * v);
    }
  }
#pragma unroll
  for (int off = 16; off; off >>= 1) {
    mx = fmaxf(mx, __shfl_xor(mx, off, 32));
    my = fmaxf(my, __shfl_xor(my, off, 32));
  }
  float sx = 0.f, sxw = 0.f, sy = 0.f, syw = 0.f;
#pragma unroll 5
  for (int i = 0; i < 25; ++i) {
    const int a2 = i * 32 + l32;
    if (a2 < 784) {
      const float v = rowp[a2];
      const int a = a2 / 28; const int bb = a2 - a * 28;
      const float ex = __expf((g[a] * v - mx) * 100.f);
      const float ey = __expf((g[32 + bb] * v - my) * 100.f);
      sx += ex; sxw += (float)a * ex;
      sy += ey; syw += (float)bb * ey;
    }
  }
#pragma unroll
  for (int off = 16; off; off >>= 1) {
    sx += __shfl_xor(sx, off, 32); sxw += __shfl_xor(sxw, off, 32);
    sy += __shfl_xor(sy, off, 32); syw += __shfl_xor(syw, off, 32);
  }
  if (l32 == 0) {
    const int uv = uv0 + row;
    float* op = m0 + (size_t)nt * 3 * 784 + uv;
    op[0]    = fmaxf(sxw / sx, 0.f);
    op[784]  = fmaxf(syw / sy, 0.f);
    op[1568] = fmaxf(bv, 0.f);
  }
}

// ---------------------------------------------------------------------------
// border_zero: zero the 108 border pixels of padded m1/m2/m3 (+ nothing else).
// chunks of 16B: per (b, bp): 8 (m1) + 16 (m2) + 16 (m3). grid 473 x 256.
// ---------------------------------------------------------------------------
__global__ __launch_bounds__(256) void border_zero_kernel(
    ushort* __restrict__ m1, ushort* __restrict__ m2, ushort* __restrict__ m3) {
  const int idx = blockIdx.x * 256 + threadIdx.x;
  if (idx >= 28 * 108 * 40) return;
  const int c = idx % 40;
  const int rest = idx / 40;
  const int bp = rest % 108;
  const int b = rest / 108;
  int ipo;
  if (bp < 28) ipo = bp;
  else if (bp < 56) ipo = 756 + (bp - 28);
  else {
    const int r = 1 + (bp - 56) / 2;
    ipo = r * 28 + ((bp - 56) & 1) * 27;
  }
  const bf16x8 z = {0,0,0,0,0,0,0,0};
  if (c < 8)       *(bf16x8*)(m1 + ((size_t)b * 784 + ipo) * 64  + c * 8) = z;
  else if (c < 24) *(bf16x8*)(m2 + ((size_t)b * 784 + ipo) * 128 + (c - 8) * 8) = z;
  else             *(bf16x8*)(m3 + ((size_t)b * 784 + ipo) * 128 + (c - 24) * 8) = z;
}

// ---------------------------------------------------------------------------
// conv1: 3 -> 64, K=5, fp32 direct; writes bf16 padded ch-last m1 (interior).
// grid (4 co-tiles, 3 pix-groups, 28 b), 256 thr.
// ---------------------------------------------------------------------------
__global__ __launch_bounds__(256) void conv1_kernel(const float* __restrict__ m0,
    const float* __restrict__ w, const float* __restrict__ bias,
    ushort* __restrict__ out) {
  const int b = blockIdx.z;
  const int pg = blockIdx.y;
  const int co0 = blockIdx.x * 16;
  const int tid = threadIdx.x;
  __shared__ float il[3 * 784];
  __shared__ float wl[75 * 16];
  const float* ip = m0 + (size_t)b * 2352;
  for (int i = tid; i < 2352; i += 256) il[i] = ip[i];
  for (int i = tid; i < 1200; i += 256) {
    const int c = i & 15, rest = i >> 4;
    wl[i] = w[(size_t)(co0 + c) * 75 + rest];
  }
  __syncthreads();
  const int pix = pg * 256 + tid;
  if (pix >= 676) return;
  const int py = pix / 26, px = pix - py * 26;
  float acc[16];
#pragma unroll
  for (int c = 0; c < 16; ++c) acc[c] = 0.f;
  for (int ci = 0; ci < 3; ++ci) {
#pragma unroll
    for (int dy = 0; dy < 5; ++dy) {
      const int iy = py + dy - 1;
      if ((unsigned)iy >= 28u) continue;
#pragma unroll
      for (int dx = 0; dx < 5; ++dx) {
        const int ix = px + dx - 1;
        if ((unsigned)ix >= 28u) continue;
        const float v = il[ci * 784 + iy * 28 + ix];
        const float* wp = &wl[(ci * 25 + dy * 5 + dx) * 16];
#pragma unroll
        for (int c4 = 0; c4 < 16; c4 += 4) {
          const float4 wv = *(const float4*)&wp[c4];
          acc[c4 + 0] += wv.x * v; acc[c4 + 1] += wv.y * v;
          acc[c4 + 2] += wv.z * v; acc[c4 + 3] += wv.w * v;
        }
      }
    }
  }
  const int ipo = (py + 1) * 28 + px + 1;
  ushort* op = out + ((size_t)b * 784 + ipo) * 64 + co0;
#pragma unroll
  for (int c = 0; c < 16; ++c)
    op[c] = f2bf(fmaxf(acc[c] + bias[co0 + c], 0.f));
}

// ---------------------------------------------------------------------------
// conv_lds: MFMA implicit-GEMM conv, LDS double-buffered K-loop (m97 style).
// Block 256 thr = 4 waves (2M x 2N). Tile BM pixels x 128 couts, BK=32.
// A staged via per-lane-gather global_load_lds into [kq4][BM][8k] (linear),
// B staged from pre-packed Bp (contiguous slice). grid (ceil(18928/BM), COUT/128).
// ---------------------------------------------------------------------------
template<int CIN, int COUT, int BM, bool FINAL>
__global__ __launch_bounds__(256) void conv_lds_kernel(
    const ushort* __restrict__ in, const ushort* __restrict__ Bp,
    const float* __restrict__ bias, ushort* __restrict__ outp,
    float* __restrict__ outf) {
  constexpr int KC = CIN * 9 / 32;          // 18 or 36
  constexpr int CPG = CIN / 32;             // k-chunks per tap
  constexpr int N16 = COUT / 16;
  constexpr int MF = BM / 32;               // M-frags per wave
  constexpr int PA = BM / 64;               // A staging passes
  constexpr int ABYTES = BM * 64;           // bytes per A buffer
  __shared__ __align__(16) char lds[2 * ABYTES + 16384];
  const int tid = threadIdx.x;
  const int w = tid >> 6, l = tid & 63;
  const int wm = w >> 1, wn = w & 1;
  const int lr = l & 15, lq = l >> 4;
  const int mt = blockIdx.x, nt = blockIdx.y;

  // per-pass A gather bases (pixel fixed per thread; tap/ci vary per kc)
  size_t srcA[PA];
#pragma unroll
  for (int p = 0; p < PA; ++p) {
    const int e = p * 256 + tid;
    const int P = e % BM, kq = e / BM;
    int GP = mt * BM + P;
    if (GP > 18927) GP = 18927;
    const int b = GP / 676, pp = GP - b * 676;
    const int ipb = pp + 2 * (pp / 26);
    srcA[p] = ((size_t)b * 784 + ipb) * CIN + kq * 8;
  }

  auto stage = [&](int kc, int buf) {
    const int tap = kc / CPG;
    const int ktoff = ((tap / 3) * 28 + (tap - (tap / 3) * 3)) * CIN +
                      (kc - tap * CPG) * 32;
#pragma unroll
    for (int p = 0; p < PA; ++p)
      glds16(in + srcA[p] + ktoff,
             lds + buf * ABYTES + p * 4096 + w * 1024);
    const ushort* bsrc = Bp + ((size_t)kc * N16 + nt * 8) * 512;
#pragma unroll
    for (int p = 0; p < 2; ++p)
      glds16(bsrc + p * 2048 + tid * 8,
             lds + 2 * ABYTES + buf * 8192 + p * 4096 + w * 1024);
  };

  f32x4 acc[MF][4];
#pragma unroll
  for (int mf = 0; mf < MF; ++mf)
#pragma unroll
    for (int nf = 0; nf < 4; ++nf) { f32x4 z = {0.f,0.f,0.f,0.f}; acc[mf][nf] = z; }

  stage(0, 0);
  __syncthreads();
  int buf = 0;
  for (int kc = 0; kc < KC; ++kc) {
    if (kc + 1 < KC) stage(kc + 1, buf ^ 1);
    const char* Ab = lds + buf * ABYTES;
    const char* Bb = lds + 2 * ABYTES + buf * 8192;
    bf16x8 afr[MF], bfr[4];
#pragma unroll
    for (int mf = 0; mf < MF; ++mf)
      afr[mf] = *(const bf16x8*)(Ab + lq * (BM * 16) +
                                 (wm * (BM / 2) + mf * 16 + lr) * 16);
#pragma unroll
    for (int nf = 0; nf < 4; ++nf)
      bfr[nf] = *(const bf16x8*)(Bb + ((wn * 4 + nf) * 64 + l) * 16);
#pragma unroll
    for (int mf = 0; mf < MF; ++mf)
#pragma unroll
      for (int nf = 0; nf < 4; ++nf)
        acc[mf][nf] = __builtin_amdgcn_mfma_f32_16x16x32_bf16(
            afr[mf], bfr[nf], acc[mf][nf], 0, 0, 0);
    __syncthreads();
    buf ^= 1;
  }

#pragma unroll
  for (int nf = 0; nf < 4; ++nf) {
    const int co = nt * 128 + wn * 64 + nf * 16 + lr;
    const float bvv = bias[co];
#pragma unroll
    for (int mf = 0; mf < MF; ++mf) {
#pragma unroll
      for (int r = 0; r < 4; ++r) {
        const int P = mt * BM + wm * (BM / 2) + mf * 16 + lq * 4 + r;
        if (P < 18928) {
          const int b = P / 676, pp = P - b * 676;
          const float v = acc[mf][nf][r] + bvv;
          if constexpr (FINAL) {
            outf[((size_t)b * COUT + co) * 676 + pp] = v;
          } else {
            const int ipo = pp + 2 * (pp / 26) + 29;
            outp[((size_t)b * 784 + ipo) * COUT + co] = f2bf(fmaxf(v, 0.f));
          }
        }
      }
    }
  }
}

// ---------------------------------------------------------------------------
// final_reduce: r[n][c] = relu( y[n][c]/6272 + sum(m4)/4732 )
// ---------------------------------------------------------------------------
__global__ __launch_bounds__(256) void final_reduce_kernel(
    const float* __restrict__ y, const float* __restrict__ m4,
    float* __restrict__ r) {
  const int nc = blockIdx.x;
  const int n = nc >> 8, c = nc & 255;
  const int tid = threadIdx.x;
  float s2 = 0.f;
  for (int t = 0; t < 7; ++t) {
    const float* ms = m4 + ((size_t)(n * 7 + t) * 256 + c) * 676;
    for (int i = tid; i < 676; i += 256) s2 += ms[i];
  }
#pragma unroll
  for (int off = 32; off; off >>= 1) s2 += __shfl_down(s2, off);
  __shared__ float red[4];
  if ((tid & 63) == 0) red[tid >> 6] = s2;
  __syncthreads();
  if (tid == 0) {
    const float tot = red[0] + red[1] + red[2] + red[3];
    r[nc] = fmaxf(y[nc] * (1.f / 6272.f) + tot * (1.f / 4732.f), 0.f);
  }
}

__global__ __launch_bounds__(256) void linear_kernel(const float* __restrict__ r,
    const float* __restrict__ lw, const float* __restrict__ lb,
    float* __restrict__ out) {
  const int n = blockIdx.x;
  const int j = threadIdx.x;
  __shared__ float rl[256];
  rl[j] = r[n * 256 + j];
  __syncthreads();
  float acc = lb[j];
  const float* w = lw + (size_t)j * 256;
#pragma unroll 4
  for (int c = 0; c < 256; c += 4) {
    const float4 wv = *(const float4*)&w[c];
    acc += wv.x * rl[c] + wv.y * rl[c + 1] + wv.z * rl[c + 2] + wv.w * rl[c + 3];
  }
  out[n * 256 + j] = acc;
}

extern "C" void kernel_launch(void* const* d_in, const int* in_sizes, int n_in,
                              void* d_out, int out_size, void* d_ws, size_t ws_size,
                              hipStream_t stream) {
  const float* x      = (const float*)d_in[0];
  const float* corr_w = (const float*)d_in[1];
  const float* corr_b = (const float*)d_in[2];
  const float* mw1 = (const float*)d_in[3];
  const float* mb1 = (const float*)d_in[4];
  const float* mw2 = (const float*)d_in[5];
  const float* mb2 = (const float*)d_in[6];
  const float* mw3 = (const float*)d_in[7];
  const float* mb3 = (const float*)d_in[8];
  const float* mw4 = (const float*)d_in[9];
  const float* mb4 = (const float*)d_in[10];
  const float* lin_w = (const float*)d_in[11];
  const float* lin_b = (const float*)d_in[12];
  float* out = (float*)d_out;
  char* wsb = (char*)d_ws;

  // workspace map (bytes), total 34.87 MB (ws >= 38.77 MB proven in round 1).
  // xh/xl/tmt dead after score; m1..m4 alias them (all written after score).
  ushort* xh  = (ushort*)(wsb + 0);          // 12,845,056
  ushort* xl  = (ushort*)(wsb + 12845056);   // -> 25,690,112
  ushort* tmt = (ushort*)(wsb + 25690112);   // -> 32,112,640
  float*  m4  = (float*)(wsb + 0);           // 19,382,272 (conv4 out)
  ushort* m1  = (ushort*)(wsb + 19382272);   // -> 22,192,128  bf16 padded
  ushort* m2  = (ushort*)(wsb + 22192128);   // -> 27,811,840
  ushort* m3  = (ushort*)(wsb + 27811840);   // -> 33,431,552
  float*  m0  = (float*)(wsb + 33431552);    // -> 33,694,976
  float*  rr  = (float*)(wsb + 33694976);    // -> 33,699,072
  ushort* Bp2 = (ushort*)(wsb + 33699072);   // -> 33,846,528
  ushort* Bp3 = (ushort*)(wsb + 33846528);   // -> 34,141,440
  ushort* Bp4 = (ushort*)(wsb + 34141440);   // -> 34,731,264
  ushort* Bph = (ushort*)(wsb + 34731264);   // -> 34,796,800
  ushort* Bpl = (ushort*)(wsb + 34796800);   // -> 34,862,336
  float*  y   = (float*)(wsb + 34862336);    // -> 34,866,432

  // all weight packs + y-zero in one dispatch (549,888 items)
  pack_all_kernel<<<dim3(2148), 256, 0, stream>>>(
      corr_w, mw2, mw3, mw4, Bph, Bpl, Bp2, Bp3, Bp4, y);

  xb_kernel<<<dim3(13, 4, 32), 256, 0, stream>>>(x, xh, xl, y);
  tm_gemm_kernel<<<dim3(196, 4), 256, 0, stream>>>(xh, xl, Bph, Bpl, corr_b, tmt);
  score_kernel<<<dim3(49, 28), 512, 0, stream>>>(tmt, m0);

  // zero padded borders of m1/m2/m3 (regions alias dead xb/tmt -> after score)
  border_zero_kernel<<<dim3(473), 256, 0, stream>>>(m1, m2, m3);

  conv1_kernel<<<dim3(4, 3, 28), 256, 0, stream>>>(m0, mw1, mb1, m1);
  conv_lds_kernel<64, 128, 64, false><<<dim3(296, 1), 256, 0, stream>>>(
      m1, Bp2, mb2, m2, nullptr);
  conv_lds_kernel<128, 128, 64, false><<<dim3(296, 1), 256, 0, stream>>>(
      m2, Bp3, mb3, m3, nullptr);
  conv_lds_kernel<128, 256, 128, true><<<dim3(148, 2), 256, 0, stream>>>(
      m3, Bp4, mb4, nullptr, m4);
  final_reduce_kernel<<<dim3(1024), 256, 0, stream>>>(y, m4, rr);
  linear_kernel<<<dim3(4), 256, 0, stream>>>(rr, lin_w, lin_b, out);
}

// Round 8
// 280.109 us; speedup vs baseline: 3.8766x; 1.0314x over previous
//
#include <hip/hip_runtime.h>

// Pipeline (fixed shapes):
// x[4][256][8][28][28] fp32
//  -> xb (relu, bf16 hi/lo, ch-last; fused x-mean atomicAdd into y)
//  -> tm_gemm (MFMA hi/lo ~fp32, A read once)  tmt [25088][128] bf16
//  -> score (MFMA GEMM + argmax + 2 softmax, lane-=bb softmax) m0 [28][3][784]
//  -> conv1 fp32 direct            m1 [28][784][64]  bf16 padded ch-last
//  -> conv_lds 2/3/4 (MFMA implicit GEMM, LDS dbuf via global_load_lds)
//  -> final_reduce (y + m4) + linear -> out [4][256] fp32

#define NORM_INV 0.07978845608028654f   // 1/(sqrt(2*pi)*5)

typedef __attribute__((ext_vector_type(8))) short bf16x8;
typedef __attribute__((ext_vector_type(4))) float f32x4;

__device__ inline ushort f2bf(float v) {
  union { float f; uint u; } c; c.f = v;
  const uint u = c.u + 0x7FFFu + ((c.u >> 16) & 1u);   // RNE
  return (ushort)(u >> 16);
}
__device__ inline float bf2f(ushort h) {
  union { uint u; float f; } c; c.u = ((uint)h) << 16;
  return c.f;
}

// async global->LDS, 16B per lane. dest is wave-uniform base (+lane*16 HW).
__device__ __forceinline__ void glds16(const void* g, void* l) {
  __builtin_amdgcn_global_load_lds(
      (const __attribute__((address_space(1))) void*)g,
      (__attribute__((address_space(3))) void*)l, 16, 0, 0);
}

// ---------------------------------------------------------------------------
// pack_all: corr_w hi/lo + conv2/3/4 weight packs + zero y. One dispatch.
// ---------------------------------------------------------------------------
__device__ __forceinline__ void pack_w_one(const float* __restrict__ w,
    ushort* __restrict__ Bp, int CIN, int N16, int idx) {
  const int j = idx & 7;
  const int l = (idx >> 3) & 63;
  const int rest = idx >> 9;
  const int n16 = rest % N16;
  const int kc = rest / N16;
  const int co = n16 * 16 + (l & 15);
  const int kk = kc * 32 + (l >> 4) * 8 + j;
  const int tap = kk / CIN;
  const int ci = kk - tap * CIN;
  Bp[idx] = f2bf(w[((size_t)co * CIN + ci) * 9 + tap]);
}

__global__ __launch_bounds__(256) void pack_all_kernel(
    const float* __restrict__ cw, const float* __restrict__ mw2,
    const float* __restrict__ mw3, const float* __restrict__ mw4,
    ushort* __restrict__ bph, ushort* __restrict__ bpl,
    ushort* __restrict__ bp2, ushort* __restrict__ bp3,
    ushort* __restrict__ bp4, float* __restrict__ y) {
  int idx = blockIdx.x * 256 + threadIdx.x;
  if (idx < 32768) {            // corr_w hi/lo: [8 kc][8 n16][64][8]
    const int j = idx & 7, l = (idx >> 3) & 63, rest = idx >> 9;
    const int n16 = rest & 7, kc = rest >> 3;
    const int co = n16 * 16 + (l & 15);
    const int k = kc * 32 + (l >> 4) * 8 + j;
    const float v = cw[co * 256 + k];
    const ushort h = f2bf(v);
    bph[idx] = h;
    bpl[idx] = f2bf(v - bf2f(h));
    return;
  }
  idx -= 32768;
  if (idx < 73728)  { pack_w_one(mw2, bp2, 64, 8, idx);  return; }
  idx -= 73728;
  if (idx < 147456) { pack_w_one(mw3, bp3, 128, 8, idx); return; }
  idx -= 147456;
  if (idx < 294912) { pack_w_one(mw4, bp4, 128, 16, idx); return; }
  idx -= 294912;
  if (idx < 1024) y[idx] = 0.f;
}

// ---------------------------------------------------------------------------
// xb: x[n][c][t][hw] -> ch-last bf16 hi/lo with relu; fused raw-x mean -> y.
// grid (13 pix-tiles of 64, 4 c-tiles of 64, 32 nt), 256 thr.
// ---------------------------------------------------------------------------
__global__ __launch_bounds__(256) void xb_kernel(const float* __restrict__ x,
    ushort* __restrict__ xh, ushort* __restrict__ xl, float* __restrict__ y) {
  const int tid = threadIdx.x;
  const int p0 = blockIdx.x * 64;
  const int c0 = blockIdx.y * 64;
  const int nt = blockIdx.z;
  const int n = nt >> 3, t = nt & 7;
  __shared__ float tile[64][65];
  const float* xp = x + (((size_t)n * 256 + c0) * 8 + t) * 784;
#pragma unroll
  for (int i = 0; i < 4; ++i) {            // float4 loads: [64 c][16 q]
    const int idx = i * 256 + tid;
    const int c = idx >> 4, q = idx & 15;
    const int hw = p0 + q * 4;
    const float* sp = xp + (size_t)c * 6272 + hw;
    if (hw + 3 < 784) {
      const float4 v = *(const float4*)sp;
      tile[q * 4 + 0][c] = v.x; tile[q * 4 + 1][c] = v.y;
      tile[q * 4 + 2][c] = v.z; tile[q * 4 + 3][c] = v.w;
    } else {
#pragma unroll
      for (int e = 0; e < 4; ++e)
        tile[q * 4 + e][c] = (hw + e < 784) ? sp[e] : 0.f;
    }
  }
  __syncthreads();
#pragma unroll
  for (int i = 0; i < 8; ++i) {
    const int idx = i * 256 + tid;
    const int p = idx >> 5, c2 = (idx & 31) * 2;
    const int hw = p0 + p;
    if (hw < 784) {
      const size_t o = ((size_t)nt * 784 + hw) * 256 + c0 + c2;
      const float v0 = fmaxf(tile[p][c2], 0.f);
      const float v1 = fmaxf(tile[p][c2 + 1], 0.f);
      const ushort h0 = f2bf(v0), h1 = f2bf(v1);
      ushort2 hv, lv;
      hv.x = h0; hv.y = h1;
      lv.x = f2bf(v0 - bf2f(h0)); lv.y = f2bf(v1 - bf2f(h1));
      *(ushort2*)(xh + o) = hv;
      *(ushort2*)(xl + o) = lv;
    }
  }
  if (tid < 64) {
    float s = 0.f;
#pragma unroll 8
    for (int p = 0; p < 64; ++p) s += tile[p][tid];
    atomicAdd(y + n * 256 + c0 + tid, s);
  }
}

// ---------------------------------------------------------------------------
// tm GEMM: tmt[pix][co] = bf16( xb[pix][:] . cw[co][:] + cb[co] ), hi/lo MFMA.
// Wave = 16 pix x ALL 128 co (A read once). grid 392, 4 waves M-stacked.
// ---------------------------------------------------------------------------
__global__ __launch_bounds__(256) void tm_gemm_kernel(
    const ushort* __restrict__ xh, const ushort* __restrict__ xl,
    const ushort* __restrict__ bph, const ushort* __restrict__ bpl,
    const float* __restrict__ cb, ushort* __restrict__ tmt) {
  const int tid = threadIdx.x;
  const int w = tid >> 6, l = tid & 63;
  const int lr = l & 15, lq = l >> 4;
  const int mtile = blockIdx.x * 4 + w;     // 0..1567 (16-pix tiles)
  const size_t r0 = (size_t)(mtile * 16 + lr) * 256 + lq * 8;
  f32x4 acc[8];
#pragma unroll
  for (int i = 0; i < 8; ++i) { f32x4 z = {0.f,0.f,0.f,0.f}; acc[i] = z; }
#pragma unroll
  for (int kc = 0; kc < 8; ++kc) {
    const bf16x8 ah = *(const bf16x8*)(xh + r0 + kc * 32);
    const bf16x8 al = *(const bf16x8*)(xl + r0 + kc * 32);
#pragma unroll
    for (int n16 = 0; n16 < 8; ++n16) {
      const size_t bo = ((size_t)(kc * 8 + n16) * 64 + l) * 8;
      const bf16x8 bh = *(const bf16x8*)(bph + bo);
      const bf16x8 bl = *(const bf16x8*)(bpl + bo);
      acc[n16] = __builtin_amdgcn_mfma_f32_16x16x32_bf16(ah, bh, acc[n16], 0,0,0);
      acc[n16] = __builtin_amdgcn_mfma_f32_16x16x32_bf16(al, bh, acc[n16], 0,0,0);
      acc[n16] = __builtin_amdgcn_mfma_f32_16x16x32_bf16(ah, bl, acc[n16], 0,0,0);
    }
  }
#pragma unroll
  for (int n16 = 0; n16 < 8; ++n16) {
    const int co = n16 * 16 + lr;
    const float bv = cb[co];
#pragma unroll
    for (int r = 0; r < 4; ++r) {
      const int pix = mtile * 16 + lq * 4 + r;
      tmt[(size_t)pix * 128 + co] = f2bf(acc[n16][r] + bv);
    }
  }
}

// ---------------------------------------------------------------------------
// score: MFMA GEMM (16 uv x 784 ab, K=128) + argmax + double softmax.
// 512 thr = 8 waves. Softmax: 32 lanes/row, lane = bb column, loop a.
// LDS 52.0 KB -> 3 blocks/CU. grid (49, 28).
// ---------------------------------------------------------------------------
__global__ __launch_bounds__(512) void score_kernel(const ushort* __restrict__ tmt,
    float* __restrict__ m0) {
  const int tid = threadIdx.x;
  const int nt = blockIdx.y;
  const int n = nt / 7, t = nt % 7;
  const int uv0 = blockIdx.x * 16;
  const ushort* bfp = tmt + (size_t)(n * 8 + t) * 784 * 128;
  const ushort* bhp = tmt + (size_t)(n * 8 + t + 1) * 784 * 128;
  __shared__ float sc[16 * 785];
  __shared__ float gxs[16][28];
  const int w = tid >> 6;
  const int l = tid & 63;
  const int lr = l & 15, lq = l >> 4;
  bf16x8 af[4];
#pragma unroll
  for (int kc = 0; kc < 4; ++kc)
    af[kc] = *(const bf16x8*)(bfp + (uv0 + lr) * 128 + kc * 32 + lq * 8);
  f32x4 acc[7];
#pragma unroll
  for (int i = 0; i < 7; ++i) { f32x4 z = {0.f,0.f,0.f,0.f}; acc[i] = z; }
#pragma unroll
  for (int i = 0; i < 7; ++i) {
    const int nf = i * 8 + w;
    if (nf < 49) {
      const ushort* bp = bhp + (nf * 16 + lr) * 128 + lq * 8;
      const bf16x8 b0 = *(const bf16x8*)(bp);
      const bf16x8 b1 = *(const bf16x8*)(bp + 32);
      const bf16x8 b2 = *(const bf16x8*)(bp + 64);
      const bf16x8 b3 = *(const bf16x8*)(bp + 96);
      acc[i] = __builtin_amdgcn_mfma_f32_16x16x32_bf16(af[0], b0, acc[i], 0,0,0);
      acc[i] = __builtin_amdgcn_mfma_f32_16x16x32_bf16(af[1], b1, acc[i], 0,0,0);
      acc[i] = __builtin_amdgcn_mfma_f32_16x16x32_bf16(af[2], b2, acc[i], 0,0,0);
      acc[i] = __builtin_amdgcn_mfma_f32_16x16x32_bf16(af[3], b3, acc[i], 0,0,0);
    }
  }
#pragma unroll
  for (int i = 0; i < 7; ++i) {
    const int nf = i * 8 + w;
    if (nf < 49) {
#pragma unroll
      for (int r = 0; r < 4; ++r)
        sc[(lq * 4 + r) * 785 + nf * 16 + lr] = acc[i][r];
    }
  }
  __syncthreads();
  // ---- softmax: 32 lanes per uv row; lane = bb (cols 0..27), loop a
  const int row = tid >> 5, l32 = tid & 31;
  const bool act = l32 < 28;
  const float* rowp = &sc[row * 785];
  // pass 1: per-lane max over a (bvp) + global argmax (first-index ties)
  float bv = -1e30f; int bi = 1 << 20;
#pragma unroll
  for (int a = 0; a < 28; ++a) {
    if (act) {
      const float v = rowp[a * 28 + l32];
      if (v > bv) { bv = v; bi = a * 28 + l32; }
    }
  }
  const float bvp = bv;                     // pre-reduce per-lane max
#pragma unroll
  for (int off = 16; off; off >>= 1) {
    const float ov = __shfl_xor(bv, off, 32);
    const int oi = __shfl_xor(bi, off, 32);
    if (ov > bv || (ov == bv && oi < bi)) { bv = ov; bi = oi; }
  }
  const int ast = bi / 28;
  const int bst = bi - ast * 28;
  // gaussian factors: gx table (per row), gy lane-constant register
  if (act) gxs[row][l32] = __expf((float)(l32 - ast) * 0.04f) * NORM_INV;
  const float gy = __expf((float)(l32 - bst) * 0.04f) * NORM_INV;
  // pass 2: mx = max(gx*v); my per-lane = gy * bvp (gy>0 factors out)
  float mx = -1e30f;
#pragma unroll
  for (int a = 0; a < 28; ++a) {
    if (act) mx = fmaxf(mx, gxs[row][a] * rowp[a * 28 + l32]);
  }
  float my = act ? gy * bvp : -1e30f;
#pragma unroll
  for (int off = 16; off; off >>= 1) {
    mx = fmaxf(mx, __shfl_xor(mx, off, 32));
    my = fmaxf(my, __shfl_xor(my, off, 32));
  }
  // pass 3: stabilized sums; syw = l32 * sy (weight lane-constant)
  float sx = 0.f, sxw = 0.f, sy = 0.f;
#pragma unroll
  for (int a = 0; a < 28; ++a) {
    if (act) {
      const float v = rowp[a * 28 + l32];
      const float ex = __expf((gxs[row][a] * v - mx) * 100.f);
      const float ey = __expf((gy * v - my) * 100.f);
      sx += ex; sxw += (float)a * ex;
      sy += ey;
    }
  }
  float syw = (float)l32 * sy;
#pragma unroll
  for (int off = 16; off; off >>= 1) {
    sx += __shfl_xor(sx, off, 32); sxw += __shfl_xor(sxw, off, 32);
    sy += __shfl_xor(sy, off, 32); syw += __shfl_xor(syw, off, 32);
  }
  if (l32 == 0) {
    const int uv = uv0 + row;
    float* op = m0 + (size_t)nt * 3 * 784 + uv;
    op[0]    = fmaxf(sxw / sx, 0.f);
    op[784]  = fmaxf(syw / sy, 0.f);
    op[1568] = fmaxf(bv, 0.f);
  }
}

// ---------------------------------------------------------------------------
// border_zero: zero the 108 border pixels of padded m1/m2/m3.
// ---------------------------------------------------------------------------
__global__ __launch_bounds__(256) void border_zero_kernel(
    ushort* __restrict__ m1, ushort* __restrict__ m2, ushort* __restrict__ m3) {
  const int idx = blockIdx.x * 256 + threadIdx.x;
  if (idx >= 28 * 108 * 40) return;
  const int c = idx % 40;
  const int rest = idx / 40;
  const int bp = rest % 108;
  const int b = rest / 108;
  int ipo;
  if (bp < 28) ipo = bp;
  else if (bp < 56) ipo = 756 + (bp - 28);
  else {
    const int r = 1 + (bp - 56) / 2;
    ipo = r * 28 + ((bp - 56) & 1) * 27;
  }
  const bf16x8 z = {0,0,0,0,0,0,0,0};
  if (c < 8)       *(bf16x8*)(m1 + ((size_t)b * 784 + ipo) * 64  + c * 8) = z;
  else if (c < 24) *(bf16x8*)(m2 + ((size_t)b * 784 + ipo) * 128 + (c - 8) * 8) = z;
  else             *(bf16x8*)(m3 + ((size_t)b * 784 + ipo) * 128 + (c - 24) * 8) = z;
}

// ---------------------------------------------------------------------------
// conv1: 3 -> 64, K=5, fp32 direct; writes bf16 padded ch-last m1 (interior).
// ---------------------------------------------------------------------------
__global__ __launch_bounds__(256) void conv1_kernel(const float* __restrict__ m0,
    const float* __restrict__ w, const float* __restrict__ bias,
    ushort* __restrict__ out) {
  const int b = blockIdx.z;
  const int pg = blockIdx.y;
  const int co0 = blockIdx.x * 16;
  const int tid = threadIdx.x;
  __shared__ float il[3 * 784];
  __shared__ float wl[75 * 16];
  const float* ip = m0 + (size_t)b * 2352;
  for (int i = tid; i < 2352; i += 256) il[i] = ip[i];
  for (int i = tid; i < 1200; i += 256) {
    const int c = i & 15, rest = i >> 4;
    wl[i] = w[(size_t)(co0 + c) * 75 + rest];
  }
  __syncthreads();
  const int pix = pg * 256 + tid;
  if (pix >= 676) return;
  const int py = pix / 26, px = pix - py * 26;
  float acc[16];
#pragma unroll
  for (int c = 0; c < 16; ++c) acc[c] = 0.f;
  for (int ci = 0; ci < 3; ++ci) {
#pragma unroll
    for (int dy = 0; dy < 5; ++dy) {
      const int iy = py + dy - 1;
      if ((unsigned)iy >= 28u) continue;
#pragma unroll
      for (int dx = 0; dx < 5; ++dx) {
        const int ix = px + dx - 1;
        if ((unsigned)ix >= 28u) continue;
        const float v = il[ci * 784 + iy * 28 + ix];
        const float* wp = &wl[(ci * 25 + dy * 5 + dx) * 16];
#pragma unroll
        for (int c4 = 0; c4 < 16; c4 += 4) {
          const float4 wv = *(const float4*)&wp[c4];
          acc[c4 + 0] += wv.x * v; acc[c4 + 1] += wv.y * v;
          acc[c4 + 2] += wv.z * v; acc[c4 + 3] += wv.w * v;
        }
      }
    }
  }
  const int ipo = (py + 1) * 28 + px + 1;
  ushort* op = out + ((size_t)b * 784 + ipo) * 64 + co0;
#pragma unroll
  for (int c = 0; c < 16; ++c)
    op[c] = f2bf(fmaxf(acc[c] + bias[co0 + c], 0.f));
}

// ---------------------------------------------------------------------------
// conv_lds: MFMA implicit-GEMM conv, LDS double-buffered (global_load_lds).
// Block 256 thr = 4 waves (2M x 2N). Tile BM pixels x 128 couts, BK=32.
// ---------------------------------------------------------------------------
template<int CIN, int COUT, int BM, bool FINAL>
__global__ __launch_bounds__(256) void conv_lds_kernel(
    const ushort* __restrict__ in, const ushort* __restrict__ Bp,
    const float* __restrict__ bias, ushort* __restrict__ outp,
    float* __restrict__ outf) {
  constexpr int KC = CIN * 9 / 32;
  constexpr int CPG = CIN / 32;
  constexpr int N16 = COUT / 16;
  constexpr int MF = BM / 32;
  constexpr int PA = BM / 64;
  constexpr int ABYTES = BM * 64;
  __shared__ __align__(16) char lds[2 * ABYTES + 16384];
  const int tid = threadIdx.x;
  const int w = tid >> 6, l = tid & 63;
  const int wm = w >> 1, wn = w & 1;
  const int lr = l & 15, lq = l >> 4;
  const int mt = blockIdx.x, nt = blockIdx.y;

  size_t srcA[PA];
#pragma unroll
  for (int p = 0; p < PA; ++p) {
    const int e = p * 256 + tid;
    const int P = e % BM, kq = e / BM;
    int GP = mt * BM + P;
    if (GP > 18927) GP = 18927;
    const int b = GP / 676, pp = GP - b * 676;
    const int ipb = pp + 2 * (pp / 26);
    srcA[p] = ((size_t)b * 784 + ipb) * CIN + kq * 8;
  }

  auto stage = [&](int kc, int buf) {
    const int tap = kc / CPG;
    const int ktoff = ((tap / 3) * 28 + (tap - (tap / 3) * 3)) * CIN +
                      (kc - tap * CPG) * 32;
#pragma unroll
    for (int p = 0; p < PA; ++p)
      glds16(in + srcA[p] + ktoff,
             lds + buf * ABYTES + p * 4096 + w * 1024);
    const ushort* bsrc = Bp + ((size_t)kc * N16 + nt * 8) * 512;
#pragma unroll
    for (int p = 0; p < 2; ++p)
      glds16(bsrc + p * 2048 + tid * 8,
             lds + 2 * ABYTES + buf * 8192 + p * 4096 + w * 1024);
  };

  f32x4 acc[MF][4];
#pragma unroll
  for (int mf = 0; mf < MF; ++mf)
#pragma unroll
    for (int nf = 0; nf < 4; ++nf) { f32x4 z = {0.f,0.f,0.f,0.f}; acc[mf][nf] = z; }

  stage(0, 0);
  __syncthreads();
  int buf = 0;
  for (int kc = 0; kc < KC; ++kc) {
    if (kc + 1 < KC) stage(kc + 1, buf ^ 1);
    const char* Ab = lds + buf * ABYTES;
    const char* Bb = lds + 2 * ABYTES + buf * 8192;
    bf16x8 afr[MF], bfr[4];
#pragma unroll
    for (int mf = 0; mf < MF; ++mf)
      afr[mf] = *(const bf16x8*)(Ab + lq * (BM * 16) +
                                 (wm * (BM / 2) + mf * 16 + lr) * 16);
#pragma unroll
    for (int nf = 0; nf < 4; ++nf)
      bfr[nf] = *(const bf16x8*)(Bb + ((wn * 4 + nf) * 64 + l) * 16);
#pragma unroll
    for (int mf = 0; mf < MF; ++mf)
#pragma unroll
      for (int nf = 0; nf < 4; ++nf)
        acc[mf][nf] = __builtin_amdgcn_mfma_f32_16x16x32_bf16(
            afr[mf], bfr[nf], acc[mf][nf], 0, 0, 0);
    __syncthreads();
    buf ^= 1;
  }

#pragma unroll
  for (int nf = 0; nf < 4; ++nf) {
    const int co = nt * 128 + wn * 64 + nf * 16 + lr;
    const float bvv = bias[co];
#pragma unroll
    for (int mf = 0; mf < MF; ++mf) {
#pragma unroll
      for (int r = 0; r < 4; ++r) {
        const int P = mt * BM + wm * (BM / 2) + mf * 16 + lq * 4 + r;
        if (P < 18928) {
          const int b = P / 676, pp = P - b * 676;
          const float v = acc[mf][nf][r] + bvv;
          if constexpr (FINAL) {
            outf[((size_t)b * COUT + co) * 676 + pp] = v;
          } else {
            const int ipo = pp + 2 * (pp / 26) + 29;
            outp[((size_t)b * 784 + ipo) * COUT + co] = f2bf(fmaxf(v, 0.f));
          }
        }
      }
    }
  }
}

// ---------------------------------------------------------------------------
// final_reduce: r[n][c] = relu( y[n][c]/6272 + sum(m4)/4732 )
// ---------------------------------------------------------------------------
__global__ __launch_bounds__(256) void final_reduce_kernel(
    const float* __restrict__ y, const float* __restrict__ m4,
    float* __restrict__ r) {
  const int nc = blockIdx.x;
  const int n = nc >> 8, c = nc & 255;
  const int tid = threadIdx.x;
  float s2 = 0.f;
  for (int t = 0; t < 7; ++t) {
    const float* ms = m4 + ((size_t)(n * 7 + t) * 256 + c) * 676;
    for (int i = tid; i < 676; i += 256) s2 += ms[i];
  }
#pragma unroll
  for (int off = 32; off; off >>= 1) s2 += __shfl_down(s2, off);
  __shared__ float red[4];
  if ((tid & 63) == 0) red[tid >> 6] = s2;
  __syncthreads();
  if (tid == 0) {
    const float tot = red[0] + red[1] + red[2] + red[3];
    r[nc] = fmaxf(y[nc] * (1.f / 6272.f) + tot * (1.f / 4732.f), 0.f);
  }
}

__global__ __launch_bounds__(256) void linear_kernel(const float* __restrict__ r,
    const float* __restrict__ lw, const float* __restrict__ lb,
    float* __restrict__ out) {
  const int n = blockIdx.x;
  const int j = threadIdx.x;
  __shared__ float rl[256];
  rl[j] = r[n * 256 + j];
  __syncthreads();
  float acc = lb[j];
  const float* w = lw + (size_t)j * 256;
#pragma unroll 4
  for (int c = 0; c < 256; c += 4) {
    const float4 wv = *(const float4*)&w[c];
    acc += wv.x * rl[c] + wv.y * rl[c + 1] + wv.z * rl[c + 2] + wv.w * rl[c + 3];
  }
  out[n * 256 + j] = acc;
}

extern "C" void kernel_launch(void* const* d_in, const int* in_sizes, int n_in,
                              void* d_out, int out_size, void* d_ws, size_t ws_size,
                              hipStream_t stream) {
  const float* x      = (const float*)d_in[0];
  const float* corr_w = (const float*)d_in[1];
  const float* corr_b = (const float*)d_in[2];
  const float* mw1 = (const float*)d_in[3];
  const float* mb1 = (const float*)d_in[4];
  const float* mw2 = (const float*)d_in[5];
  const float* mb2 = (const float*)d_in[6];
  const float* mw3 = (const float*)d_in[7];
  const float* mb3 = (const float*)d_in[8];
  const float* mw4 = (const float*)d_in[9];
  const float* mb4 = (const float*)d_in[10];
  const float* lin_w = (const float*)d_in[11];
  const float* lin_b = (const float*)d_in[12];
  float* out = (float*)d_out;
  char* wsb = (char*)d_ws;

  // workspace map (bytes), total 34.87 MB.
  ushort* xh  = (ushort*)(wsb + 0);          // 12,845,056
  ushort* xl  = (ushort*)(wsb + 12845056);   // -> 25,690,112
  ushort* tmt = (ushort*)(wsb + 25690112);   // -> 32,112,640
  float*  m4  = (float*)(wsb + 0);           // 19,382,272 (conv4 out)
  ushort* m1  = (ushort*)(wsb + 19382272);   // -> 22,192,128  bf16 padded
  ushort* m2  = (ushort*)(wsb + 22192128);   // -> 27,811,840
  ushort* m3  = (ushort*)(wsb + 27811840);   // -> 33,431,552
  float*  m0  = (float*)(wsb + 33431552);    // -> 33,694,976
  float*  rr  = (float*)(wsb + 33694976);    // -> 33,699,072
  ushort* Bp2 = (ushort*)(wsb + 33699072);   // -> 33,846,528
  ushort* Bp3 = (ushort*)(wsb + 33846528);   // -> 34,141,440
  ushort* Bp4 = (ushort*)(wsb + 34141440);   // -> 34,731,264
  ushort* Bph = (ushort*)(wsb + 34731264);   // -> 34,796,800
  ushort* Bpl = (ushort*)(wsb + 34796800);   // -> 34,862,336
  float*  y   = (float*)(wsb + 34862336);    // -> 34,866,432

  pack_all_kernel<<<dim3(2148), 256, 0, stream>>>(
      corr_w, mw2, mw3, mw4, Bph, Bpl, Bp2, Bp3, Bp4, y);

  xb_kernel<<<dim3(13, 4, 32), 256, 0, stream>>>(x, xh, xl, y);
  tm_gemm_kernel<<<dim3(392), 256, 0, stream>>>(xh, xl, Bph, Bpl, corr_b, tmt);
  score_kernel<<<dim3(49, 28), 512, 0, stream>>>(tmt, m0);

  border_zero_kernel<<<dim3(473), 256, 0, stream>>>(m1, m2, m3);

  conv1_kernel<<<dim3(4, 3, 28), 256, 0, stream>>>(m0, mw1, mb1, m1);
  conv_lds_kernel<64, 128, 64, false><<<dim3(296, 1), 256, 0, stream>>>(
      m1, Bp2, mb2, m2, nullptr);
  conv_lds_kernel<128, 128, 64, false><<<dim3(296, 1), 256, 0, stream>>>(
      m2, Bp3, mb3, m3, nullptr);
  conv_lds_kernel<128, 256, 128, true><<<dim3(148, 2), 256, 0, stream>>>(
      m3, Bp4, mb4, nullptr, m4);
  final_reduce_kernel<<<dim3(1024), 256, 0, stream>>>(y, m4, rr);
  linear_kernel<<<dim3(4), 256, 0, stream>>>(rr, lin_w, lin_b, out);
}

// Round 9
// 278.675 us; speedup vs baseline: 3.8966x; 1.0051x over previous
//
#include <hip/hip_runtime.h>

// Pipeline (fixed shapes):
// x[4][256][8][28][28] fp32
//  -> xb (relu, bf16 hi/lo, ch-last; fused x-mean atomicAdd into y)
//  -> tm_gemm (MFMA hi/lo ~fp32, A read once)  tmt [25088][128] bf16
//  -> score (MFMA GEMM + argmax + 2 softmax, register-cached row) m0
//  -> conv1 fp32 direct            m1 [28][784][64]  bf16 padded ch-last
//  -> conv_lds 2/3/4 (MFMA implicit GEMM, LDS dbuf via global_load_lds)
//  -> final_reduce (y + m4) + linear -> out [4][256] fp32

#define NORM_INV 0.07978845608028654f   // 1/(sqrt(2*pi)*5)

typedef __attribute__((ext_vector_type(8))) short bf16x8;
typedef __attribute__((ext_vector_type(4))) float f32x4;

__device__ inline ushort f2bf(float v) {
  union { float f; uint u; } c; c.f = v;
  const uint u = c.u + 0x7FFFu + ((c.u >> 16) & 1u);   // RNE
  return (ushort)(u >> 16);
}
__device__ inline float bf2f(ushort h) {
  union { uint u; float f; } c; c.u = ((uint)h) << 16;
  return c.f;
}

// async global->LDS, 16B per lane. dest is wave-uniform base (+lane*16 HW).
__device__ __forceinline__ void glds16(const void* g, void* l) {
  __builtin_amdgcn_global_load_lds(
      (const __attribute__((address_space(1))) void*)g,
      (__attribute__((address_space(3))) void*)l, 16, 0, 0);
}

// ---------------------------------------------------------------------------
// pack_all: corr_w hi/lo + conv2/3/4 weight packs + zero y. One dispatch.
// ---------------------------------------------------------------------------
__device__ __forceinline__ void pack_w_one(const float* __restrict__ w,
    ushort* __restrict__ Bp, int CIN, int N16, int idx) {
  const int j = idx & 7;
  const int l = (idx >> 3) & 63;
  const int rest = idx >> 9;
  const int n16 = rest % N16;
  const int kc = rest / N16;
  const int co = n16 * 16 + (l & 15);
  const int kk = kc * 32 + (l >> 4) * 8 + j;
  const int tap = kk / CIN;
  const int ci = kk - tap * CIN;
  Bp[idx] = f2bf(w[((size_t)co * CIN + ci) * 9 + tap]);
}

__global__ __launch_bounds__(256) void pack_all_kernel(
    const float* __restrict__ cw, const float* __restrict__ mw2,
    const float* __restrict__ mw3, const float* __restrict__ mw4,
    ushort* __restrict__ bph, ushort* __restrict__ bpl,
    ushort* __restrict__ bp2, ushort* __restrict__ bp3,
    ushort* __restrict__ bp4, float* __restrict__ y) {
  int idx = blockIdx.x * 256 + threadIdx.x;
  if (idx < 32768) {            // corr_w hi/lo: [8 kc][8 n16][64][8]
    const int j = idx & 7, l = (idx >> 3) & 63, rest = idx >> 9;
    const int n16 = rest & 7, kc = rest >> 3;
    const int co = n16 * 16 + (l & 15);
    const int k = kc * 32 + (l >> 4) * 8 + j;
    const float v = cw[co * 256 + k];
    const ushort h = f2bf(v);
    bph[idx] = h;
    bpl[idx] = f2bf(v - bf2f(h));
    return;
  }
  idx -= 32768;
  if (idx < 73728)  { pack_w_one(mw2, bp2, 64, 8, idx);  return; }
  idx -= 73728;
  if (idx < 147456) { pack_w_one(mw3, bp3, 128, 8, idx); return; }
  idx -= 147456;
  if (idx < 294912) { pack_w_one(mw4, bp4, 128, 16, idx); return; }
  idx -= 294912;
  if (idx < 1024) y[idx] = 0.f;
}

// ---------------------------------------------------------------------------
// xb: x[n][c][t][hw] -> ch-last bf16 hi/lo with relu; fused raw-x mean -> y.
// grid (13 pix-tiles of 64, 4 c-tiles of 64, 32 nt), 256 thr.
// ---------------------------------------------------------------------------
__global__ __launch_bounds__(256) void xb_kernel(const float* __restrict__ x,
    ushort* __restrict__ xh, ushort* __restrict__ xl, float* __restrict__ y) {
  const int tid = threadIdx.x;
  const int p0 = blockIdx.x * 64;
  const int c0 = blockIdx.y * 64;
  const int nt = blockIdx.z;
  const int n = nt >> 3, t = nt & 7;
  __shared__ float tile[64][65];
  const float* xp = x + (((size_t)n * 256 + c0) * 8 + t) * 784;
#pragma unroll
  for (int i = 0; i < 4; ++i) {            // float4 loads: [64 c][16 q]
    const int idx = i * 256 + tid;
    const int c = idx >> 4, q = idx & 15;
    const int hw = p0 + q * 4;
    const float* sp = xp + (size_t)c * 6272 + hw;
    if (hw + 3 < 784) {
      const float4 v = *(const float4*)sp;
      tile[q * 4 + 0][c] = v.x; tile[q * 4 + 1][c] = v.y;
      tile[q * 4 + 2][c] = v.z; tile[q * 4 + 3][c] = v.w;
    } else {
#pragma unroll
      for (int e = 0; e < 4; ++e)
        tile[q * 4 + e][c] = (hw + e < 784) ? sp[e] : 0.f;
    }
  }
  __syncthreads();
  // phase 2: 512 items = 64 pix x 8 channel-octs; 16B hi + 16B lo per item
#pragma unroll
  for (int i = 0; i < 2; ++i) {
    const int idx = i * 256 + tid;
    const int p = idx >> 3, oct = idx & 7;
    const int hw = p0 + p;
    if (hw < 784) {
      const size_t o = ((size_t)nt * 784 + hw) * 256 + c0 + oct * 8;
      union { ushort u[8]; bf16x8 v8; } ph, pl;
#pragma unroll
      for (int e = 0; e < 8; ++e) {
        const float vv = fmaxf(tile[p][oct * 8 + e], 0.f);
        const ushort h = f2bf(vv);
        ph.u[e] = h; pl.u[e] = f2bf(vv - bf2f(h));
      }
      *(bf16x8*)(xh + o) = ph.v8;
      *(bf16x8*)(xl + o) = pl.v8;
    }
  }
  if (tid < 64) {
    float s = 0.f;
#pragma unroll 8
    for (int p = 0; p < 64; ++p) s += tile[p][tid];
    atomicAdd(y + n * 256 + c0 + tid, s);
  }
}

// ---------------------------------------------------------------------------
// tm GEMM: tmt[pix][co] = bf16( xb[pix][:] . cw[co][:] + cb[co] ), hi/lo MFMA.
// Wave = 16 pix x ALL 128 co (A read once). grid 392, 4 waves M-stacked.
// ---------------------------------------------------------------------------
__global__ __launch_bounds__(256) void tm_gemm_kernel(
    const ushort* __restrict__ xh, const ushort* __restrict__ xl,
    const ushort* __restrict__ bph, const ushort* __restrict__ bpl,
    const float* __restrict__ cb, ushort* __restrict__ tmt) {
  const int tid = threadIdx.x;
  const int w = tid >> 6, l = tid & 63;
  const int lr = l & 15, lq = l >> 4;
  const int mtile = blockIdx.x * 4 + w;     // 0..1567 (16-pix tiles)
  const size_t r0 = (size_t)(mtile * 16 + lr) * 256 + lq * 8;
  f32x4 acc[8];
#pragma unroll
  for (int i = 0; i < 8; ++i) { f32x4 z = {0.f,0.f,0.f,0.f}; acc[i] = z; }
#pragma unroll
  for (int kc = 0; kc < 8; ++kc) {
    const bf16x8 ah = *(const bf16x8*)(xh + r0 + kc * 32);
    const bf16x8 al = *(const bf16x8*)(xl + r0 + kc * 32);
#pragma unroll
    for (int n16 = 0; n16 < 8; ++n16) {
      const size_t bo = ((size_t)(kc * 8 + n16) * 64 + l) * 8;
      const bf16x8 bh = *(const bf16x8*)(bph + bo);
      const bf16x8 bl = *(const bf16x8*)(bpl + bo);
      acc[n16] = __builtin_amdgcn_mfma_f32_16x16x32_bf16(ah, bh, acc[n16], 0,0,0);
      acc[n16] = __builtin_amdgcn_mfma_f32_16x16x32_bf16(al, bh, acc[n16], 0,0,0);
      acc[n16] = __builtin_amdgcn_mfma_f32_16x16x32_bf16(ah, bl, acc[n16], 0,0,0);
    }
  }
#pragma unroll
  for (int n16 = 0; n16 < 8; ++n16) {
    const int co = n16 * 16 + lr;
    const float bv = cb[co];
#pragma unroll
    for (int r = 0; r < 4; ++r) {
      const int pix = mtile * 16 + lq * 4 + r;
      tmt[(size_t)pix * 128 + co] = f2bf(acc[n16][r] + bv);
    }
  }
}

// ---------------------------------------------------------------------------
// score: MFMA GEMM (16 uv x 784 ab, K=128) + argmax + double softmax.
// 512 thr = 8 waves. Softmax: 32 lanes/row (lane=bb, loop a), row cached in
// 28 registers (single LDS read per element). grid (49, 28).
// ---------------------------------------------------------------------------
__global__ __launch_bounds__(512) void score_kernel(const ushort* __restrict__ tmt,
    float* __restrict__ m0) {
  const int tid = threadIdx.x;
  const int nt = blockIdx.y;
  const int n = nt / 7, t = nt % 7;
  const int uv0 = blockIdx.x * 16;
  const ushort* bfp = tmt + (size_t)(n * 8 + t) * 784 * 128;      // frame t
  const ushort* bhp = tmt + (size_t)(n * 8 + t + 1) * 784 * 128;  // frame t+1
  __shared__ float sc[16 * 785];
  __shared__ float gxs[16][28];              // gx * 100 table per row
  const int w = tid >> 6;
  const int l = tid & 63;
  const int lr = l & 15, lq = l >> 4;
  bf16x8 af[4];
#pragma unroll
  for (int kc = 0; kc < 4; ++kc)
    af[kc] = *(const bf16x8*)(bfp + (uv0 + lr) * 128 + kc * 32 + lq * 8);
  f32x4 acc[7];
#pragma unroll
  for (int i = 0; i < 7; ++i) { f32x4 z = {0.f,0.f,0.f,0.f}; acc[i] = z; }
#pragma unroll
  for (int i = 0; i < 7; ++i) {
    const int nf = i * 8 + w;
    if (nf < 49) {
      const ushort* bp = bhp + (nf * 16 + lr) * 128 + lq * 8;
      const bf16x8 b0 = *(const bf16x8*)(bp);
      const bf16x8 b1 = *(const bf16x8*)(bp + 32);
      const bf16x8 b2 = *(const bf16x8*)(bp + 64);
      const bf16x8 b3 = *(const bf16x8*)(bp + 96);
      acc[i] = __builtin_amdgcn_mfma_f32_16x16x32_bf16(af[0], b0, acc[i], 0,0,0);
      acc[i] = __builtin_amdgcn_mfma_f32_16x16x32_bf16(af[1], b1, acc[i], 0,0,0);
      acc[i] = __builtin_amdgcn_mfma_f32_16x16x32_bf16(af[2], b2, acc[i], 0,0,0);
      acc[i] = __builtin_amdgcn_mfma_f32_16x16x32_bf16(af[3], b3, acc[i], 0,0,0);
    }
  }
#pragma unroll
  for (int i = 0; i < 7; ++i) {
    const int nf = i * 8 + w;
    if (nf < 49) {
#pragma unroll
      for (int r = 0; r < 4; ++r)
        sc[(lq * 4 + r) * 785 + nf * 16 + lr] = acc[i][r];
    }
  }
  __syncthreads();
  // ---- softmax: 32 lanes per uv row; lane = bb, loop a; row in registers
  const int row = tid >> 5, l32 = tid & 31;
  const bool act = l32 < 28;
  const float* rowp = &sc[row * 785];
  float v[28];
  float bv = -1e30f; int bi = 1 << 20;
#pragma unroll
  for (int a = 0; a < 28; ++a) {             // single LDS pass + argmax
    v[a] = act ? rowp[a * 28 + l32] : -1e30f;
    if (v[a] > bv) { bv = v[a]; bi = a * 28 + l32; }
  }
  const float bvp = bv;                      // per-lane max (pre-reduce)
#pragma unroll
  for (int off = 16; off; off >>= 1) {
    const float ov = __shfl_xor(bv, off, 32);
    const int oi = __shfl_xor(bi, off, 32);
    if (ov > bv || (ov == bv && oi < bi)) { bv = ov; bi = oi; }
  }
  const int ast = bi / 28;
  const int bst = bi - ast * 28;
  // gaussian factors pre-scaled by 1/ETA = 100
  if (act) gxs[row][l32] = __expf((float)(l32 - ast) * 0.04f) * (NORM_INV * 100.f);
  const float gy100 = __expf((float)(l32 - bst) * 0.04f) * (NORM_INV * 100.f);
  // maxes: mx100 over registers; my100 = gy100 * bvp (gy lane-constant > 0)
  float mx100 = -1e30f;
#pragma unroll
  for (int a = 0; a < 28; ++a) mx100 = fmaxf(mx100, gxs[row][a] * v[a]);
  float my100 = gy100 * bvp;
#pragma unroll
  for (int off = 16; off; off >>= 1) {
    mx100 = fmaxf(mx100, __shfl_xor(mx100, off, 32));
    my100 = fmaxf(my100, __shfl_xor(my100, off, 32));
  }
  // sums (register stream: 1 fma + 1 exp per element per softmax)
  float sx = 0.f, sxw = 0.f, sy = 0.f;
#pragma unroll
  for (int a = 0; a < 28; ++a) {
    const float ex = __expf(__builtin_fmaf(gxs[row][a], v[a], -mx100));
    const float ey = __expf(__builtin_fmaf(gy100, v[a], -my100));
    if (act) { sx += ex; sxw += (float)a * ex; sy += ey; }
  }
  float syw = (float)l32 * sy;
#pragma unroll
  for (int off = 16; off; off >>= 1) {
    sx += __shfl_xor(sx, off, 32); sxw += __shfl_xor(sxw, off, 32);
    sy += __shfl_xor(sy, off, 32); syw += __shfl_xor(syw, off, 32);
  }
  if (l32 == 0) {
    const int uv = uv0 + row;
    float* op = m0 + (size_t)nt * 3 * 784 + uv;
    op[0]    = fmaxf(sxw / sx, 0.f);
    op[784]  = fmaxf(syw / sy, 0.f);
    op[1568] = fmaxf(bv, 0.f);
  }
}

// ---------------------------------------------------------------------------
// border_zero: zero the 108 border pixels of padded m1/m2/m3.
// ---------------------------------------------------------------------------
__global__ __launch_bounds__(256) void border_zero_kernel(
    ushort* __restrict__ m1, ushort* __restrict__ m2, ushort* __restrict__ m3) {
  const int idx = blockIdx.x * 256 + threadIdx.x;
  if (idx >= 28 * 108 * 40) return;
  const int c = idx % 40;
  const int rest = idx / 40;
  const int bp = rest % 108;
  const int b = rest / 108;
  int ipo;
  if (bp < 28) ipo = bp;
  else if (bp < 56) ipo = 756 + (bp - 28);
  else {
    const int r = 1 + (bp - 56) / 2;
    ipo = r * 28 + ((bp - 56) & 1) * 27;
  }
  const bf16x8 z = {0,0,0,0,0,0,0,0};
  if (c < 8)       *(bf16x8*)(m1 + ((size_t)b * 784 + ipo) * 64  + c * 8) = z;
  else if (c < 24) *(bf16x8*)(m2 + ((size_t)b * 784 + ipo) * 128 + (c - 8) * 8) = z;
  else             *(bf16x8*)(m3 + ((size_t)b * 784 + ipo) * 128 + (c - 24) * 8) = z;
}

// ---------------------------------------------------------------------------
// conv1: 3 -> 64, K=5, fp32 direct; writes bf16 padded ch-last m1 (interior).
// ---------------------------------------------------------------------------
__global__ __launch_bounds__(256) void conv1_kernel(const float* __restrict__ m0,
    const float* __restrict__ w, const float* __restrict__ bias,
    ushort* __restrict__ out) {
  const int b = blockIdx.z;
  const int pg = blockIdx.y;
  const int co0 = blockIdx.x * 16;
  const int tid = threadIdx.x;
  __shared__ float il[3 * 784];
  __shared__ float wl[75 * 16];
  const float* ip = m0 + (size_t)b * 2352;
  for (int i = tid; i < 2352; i += 256) il[i] = ip[i];
  for (int i = tid; i < 1200; i += 256) {
    const int c = i & 15, rest = i >> 4;
    wl[i] = w[(size_t)(co0 + c) * 75 + rest];
  }
  __syncthreads();
  const int pix = pg * 256 + tid;
  if (pix >= 676) return;
  const int py = pix / 26, px = pix - py * 26;
  float acc[16];
#pragma unroll
  for (int c = 0; c < 16; ++c) acc[c] = 0.f;
  for (int ci = 0; ci < 3; ++ci) {
#pragma unroll
    for (int dy = 0; dy < 5; ++dy) {
      const int iy = py + dy - 1;
      if ((unsigned)iy >= 28u) continue;
#pragma unroll
      for (int dx = 0; dx < 5; ++dx) {
        const int ix = px + dx - 1;
        if ((unsigned)ix >= 28u) continue;
        const float v = il[ci * 784 + iy * 28 + ix];
        const float* wp = &wl[(ci * 25 + dy * 5 + dx) * 16];
#pragma unroll
        for (int c4 = 0; c4 < 16; c4 += 4) {
          const float4 wv = *(const float4*)&wp[c4];
          acc[c4 + 0] += wv.x * v; acc[c4 + 1] += wv.y * v;
          acc[c4 + 2] += wv.z * v; acc[c4 + 3] += wv.w * v;
        }
      }
    }
  }
  const int ipo = (py + 1) * 28 + px + 1;
  ushort* op = out + ((size_t)b * 784 + ipo) * 64 + co0;
#pragma unroll
  for (int c = 0; c < 16; ++c)
    op[c] = f2bf(fmaxf(acc[c] + bias[co0 + c], 0.f));
}

// ---------------------------------------------------------------------------
// conv_lds: MFMA implicit-GEMM conv, LDS double-buffered (global_load_lds).
// Block 256 thr = 4 waves (2M x 2N). Tile BM pixels x 128 couts, BK=32.
// ---------------------------------------------------------------------------
template<int CIN, int COUT, int BM, bool FINAL>
__global__ __launch_bounds__(256) void conv_lds_kernel(
    const ushort* __restrict__ in, const ushort* __restrict__ Bp,
    const float* __restrict__ bias, ushort* __restrict__ outp,
    float* __restrict__ outf) {
  constexpr int KC = CIN * 9 / 32;
  constexpr int CPG = CIN / 32;
  constexpr int N16 = COUT / 16;
  constexpr int MF = BM / 32;
  constexpr int PA = BM / 64;
  constexpr int ABYTES = BM * 64;
  __shared__ __align__(16) char lds[2 * ABYTES + 16384];
  const int tid = threadIdx.x;
  const int w = tid >> 6, l = tid & 63;
  const int wm = w >> 1, wn = w & 1;
  const int lr = l & 15, lq = l >> 4;
  const int mt = blockIdx.x, nt = blockIdx.y;

  size_t srcA[PA];
#pragma unroll
  for (int p = 0; p < PA; ++p) {
    const int e = p * 256 + tid;
    const int P = e % BM, kq = e / BM;
    int GP = mt * BM + P;
    if (GP > 18927) GP = 18927;
    const int b = GP / 676, pp = GP - b * 676;
    const int ipb = pp + 2 * (pp / 26);
    srcA[p] = ((size_t)b * 784 + ipb) * CIN + kq * 8;
  }

  auto stage = [&](int kc, int buf) {
    const int tap = kc / CPG;
    const int ktoff = ((tap / 3) * 28 + (tap - (tap / 3) * 3)) * CIN +
                      (kc - tap * CPG) * 32;
#pragma unroll
    for (int p = 0; p < PA; ++p)
      glds16(in + srcA[p] + ktoff,
             lds + buf * ABYTES + p * 4096 + w * 1024);
    const ushort* bsrc = Bp + ((size_t)kc * N16 + nt * 8) * 512;
#pragma unroll
    for (int p = 0; p < 2; ++p)
      glds16(bsrc + p * 2048 + tid * 8,
             lds + 2 * ABYTES + buf * 8192 + p * 4096 + w * 1024);
  };

  f32x4 acc[MF][4];
#pragma unroll
  for (int mf = 0; mf < MF; ++mf)
#pragma unroll
    for (int nf = 0; nf < 4; ++nf) { f32x4 z = {0.f,0.f,0.f,0.f}; acc[mf][nf] = z; }

  stage(0, 0);
  __syncthreads();
  int buf = 0;
  for (int kc = 0; kc < KC; ++kc) {
    if (kc + 1 < KC) stage(kc + 1, buf ^ 1);
    const char* Ab = lds + buf * ABYTES;
    const char* Bb = lds + 2 * ABYTES + buf * 8192;
    bf16x8 afr[MF], bfr[4];
#pragma unroll
    for (int mf = 0; mf < MF; ++mf)
      afr[mf] = *(const bf16x8*)(Ab + lq * (BM * 16) +
                                 (wm * (BM / 2) + mf * 16 + lr) * 16);
#pragma unroll
    for (int nf = 0; nf < 4; ++nf)
      bfr[nf] = *(const bf16x8*)(Bb + ((wn * 4 + nf) * 64 + l) * 16);
#pragma unroll
    for (int mf = 0; mf < MF; ++mf)
#pragma unroll
      for (int nf = 0; nf < 4; ++nf)
        acc[mf][nf] = __builtin_amdgcn_mfma_f32_16x16x32_bf16(
            afr[mf], bfr[nf], acc[mf][nf], 0, 0, 0);
    __syncthreads();
    buf ^= 1;
  }

#pragma unroll
  for (int nf = 0; nf < 4; ++nf) {
    const int co = nt * 128 + wn * 64 + nf * 16 + lr;
    const float bvv = bias[co];
#pragma unroll
    for (int mf = 0; mf < MF; ++mf) {
#pragma unroll
      for (int r = 0; r < 4; ++r) {
        const int P = mt * BM + wm * (BM / 2) + mf * 16 + lq * 4 + r;
        if (P < 18928) {
          const int b = P / 676, pp = P - b * 676;
          const float v = acc[mf][nf][r] + bvv;
          if constexpr (FINAL) {
            outf[((size_t)b * COUT + co) * 676 + pp] = v;
          } else {
            const int ipo = pp + 2 * (pp / 26) + 29;
            outp[((size_t)b * 784 + ipo) * COUT + co] = f2bf(fmaxf(v, 0.f));
          }
        }
      }
    }
  }
}

// ---------------------------------------------------------------------------
// final_reduce: r[n][c] = relu( y[n][c]/6272 + sum(m4)/4732 )
// ---------------------------------------------------------------------------
__global__ __launch_bounds__(256) void final_reduce_kernel(
    const float* __restrict__ y, const float* __restrict__ m4,
    float* __restrict__ r) {
  const int nc = blockIdx.x;
  const int n = nc >> 8, c = nc & 255;
  const int tid = threadIdx.x;
  float s2 = 0.f;
  for (int t = 0; t < 7; ++t) {
    const float* ms = m4 + ((size_t)(n * 7 + t) * 256 + c) * 676;
    for (int i = tid; i < 676; i += 256) s2 += ms[i];
  }
#pragma unroll
  for (int off = 32; off; off >>= 1) s2 += __shfl_down(s2, off);
  __shared__ float red[4];
  if ((tid & 63) == 0) red[tid >> 6] = s2;
  __syncthreads();
  if (tid == 0) {
    const float tot = red[0] + red[1] + red[2] + red[3];
    r[nc] = fmaxf(y[nc] * (1.f / 6272.f) + tot * (1.f / 4732.f), 0.f);
  }
}

__global__ __launch_bounds__(256) void linear_kernel(const float* __restrict__ r,
    const float* __restrict__ lw, const float* __restrict__ lb,
    float* __restrict__ out) {
  const int n = blockIdx.x;
  const int j = threadIdx.x;
  __shared__ float rl[256];
  rl[j] = r[n * 256 + j];
  __syncthreads();
  float acc = lb[j];
  const float* w = lw + (size_t)j * 256;
#pragma unroll 4
  for (int c = 0; c < 256; c += 4) {
    const float4 wv = *(const float4*)&w[c];
    acc += wv.x * rl[c] + wv.y * rl[c + 1] + wv.z * rl[c + 2] + wv.w * rl[c + 3];
  }
  out[n * 256 + j] = acc;
}

extern "C" void kernel_launch(void* const* d_in, const int* in_sizes, int n_in,
                              void* d_out, int out_size, void* d_ws, size_t ws_size,
                              hipStream_t stream) {
  const float* x      = (const float*)d_in[0];
  const float* corr_w = (const float*)d_in[1];
  const float* corr_b = (const float*)d_in[2];
  const float* mw1 = (const float*)d_in[3];
  const float* mb1 = (const float*)d_in[4];
  const float* mw2 = (const float*)d_in[5];
  const float* mb2 = (const float*)d_in[6];
  const float* mw3 = (const float*)d_in[7];
  const float* mb3 = (const float*)d_in[8];
  const float* mw4 = (const float*)d_in[9];
  const float* mb4 = (const float*)d_in[10];
  const float* lin_w = (const float*)d_in[11];
  const float* lin_b = (const float*)d_in[12];
  float* out = (float*)d_out;
  char* wsb = (char*)d_ws;

  // workspace map (bytes), total 34.87 MB.
  ushort* xh  = (ushort*)(wsb + 0);          // 12,845,056
  ushort* xl  = (ushort*)(wsb + 12845056);   // -> 25,690,112
  ushort* tmt = (ushort*)(wsb + 25690112);   // -> 32,112,640
  float*  m4  = (float*)(wsb + 0);           // 19,382,272 (conv4 out)
  ushort* m1  = (ushort*)(wsb + 19382272);   // -> 22,192,128  bf16 padded
  ushort* m2  = (ushort*)(wsb + 22192128);   // -> 27,811,840
  ushort* m3  = (ushort*)(wsb + 27811840);   // -> 33,431,552
  float*  m0  = (float*)(wsb + 33431552);    // -> 33,694,976
  float*  rr  = (float*)(wsb + 33694976);    // -> 33,699,072
  ushort* Bp2 = (ushort*)(wsb + 33699072);   // -> 33,846,528
  ushort* Bp3 = (ushort*)(wsb + 33846528);   // -> 34,141,440
  ushort* Bp4 = (ushort*)(wsb + 34141440);   // -> 34,731,264
  ushort* Bph = (ushort*)(wsb + 34731264);   // -> 34,796,800
  ushort* Bpl = (ushort*)(wsb + 34796800);   // -> 34,862,336
  float*  y   = (float*)(wsb + 34862336);    // -> 34,866,432

  pack_all_kernel<<<dim3(2148), 256, 0, stream>>>(
      corr_w, mw2, mw3, mw4, Bph, Bpl, Bp2, Bp3, Bp4, y);

  xb_kernel<<<dim3(13, 4, 32), 256, 0, stream>>>(x, xh, xl, y);
  tm_gemm_kernel<<<dim3(392), 256, 0, stream>>>(xh, xl, Bph, Bpl, corr_b, tmt);
  score_kernel<<<dim3(49, 28), 512, 0, stream>>>(tmt, m0);

  border_zero_kernel<<<dim3(473), 256, 0, stream>>>(m1, m2, m3);

  conv1_kernel<<<dim3(4, 3, 28), 256, 0, stream>>>(m0, mw1, mb1, m1);
  conv_lds_kernel<64, 128, 64, false><<<dim3(296, 1), 256, 0, stream>>>(
      m1, Bp2, mb2, m2, nullptr);
  conv_lds_kernel<128, 128, 64, false><<<dim3(296, 1), 256, 0, stream>>>(
      m2, Bp3, mb3, m3, nullptr);
  conv_lds_kernel<128, 256, 128, true><<<dim3(148, 2), 256, 0, stream>>>(
      m3, Bp4, mb4, nullptr, m4);
  final_reduce_kernel<<<dim3(1024), 256, 0, stream>>>(y, m4, rr);
  linear_kernel<<<dim3(4), 256, 0, stream>>>(rr, lin_w, lin_b, out);
}